// Round 15
// baseline (850.646 us; speedup 1.0000x reference)
//
#include <hip/hip_runtime.h>
#include <math.h>

#define HWp 16384
#define Wp 128
#define Hp 128
#define Bp 4
#define Cp 64
#define CKp 576

typedef unsigned int u32;
typedef unsigned short ushortt;
typedef __attribute__((ext_vector_type(8))) short short8;
typedef __attribute__((ext_vector_type(4))) float float4v;

__device__ __forceinline__ ushortt f2b(float f) {
  union { float f; u32 u; } x; x.f = f;
  u32 r = x.u + 0x7fff + ((x.u >> 16) & 1);
  return (ushortt)(r >> 16);
}
__device__ __forceinline__ float b2f(ushortt h) {
  union { u32 u; float f; } x; x.u = ((u32)h) << 16; return x.f;
}
__device__ __forceinline__ float blo(u32 t) {
  union { u32 u; float f; } x; x.u = t << 16; return x.f;
}
__device__ __forceinline__ float bhi(u32 t) {
  union { u32 u; float f; } x; x.u = t & 0xffff0000u; return x.f;
}
__device__ __forceinline__ void gll(const ushortt* g, ushortt* l) {
  __builtin_amdgcn_global_load_lds(
      (const __attribute__((address_space(1))) u32*)g,
      (__attribute__((address_space(3))) u32*)l, 16, 0, 0);
}

// ---------------- depthwise 7x7, pad 3, LDS-tiled (NCHW in, bf16 NCHW out) ----------------
__global__ __launch_bounds__(256)
void dwconv7_lds(const float* __restrict__ in, const float* __restrict__ w,
                 ushortt* __restrict__ out) {
  int bc = blockIdx.y;
  int tid = threadIdx.x;
  int y0 = blockIdx.x * 2;
  __shared__ float ws[49];
  __shared__ float tile[8][136];
  if (tid < 49) ws[tid] = w[(bc & 63) * 49 + tid];
  if (tid < 48) {
    int r = tid / 6, cc = tid % 6;
    tile[r][cc < 3 ? cc : 128 + cc] = 0.f;
  }
  const float* ip = in + (size_t)bc * HWp;
  #pragma unroll
  for (int i = 0; i < 4; i++) {
    int idx = tid + 256 * i;
    int r = idx >> 7, xx = idx & 127;
    int yy = y0 - 3 + r;
    tile[r][xx + 3] = (yy >= 0 && yy < Hp) ? ip[yy * Wp + xx] : 0.f;
  }
  __syncthreads();
  int ty = tid >> 7, x = tid & 127;
  float acc = 0.f;
  #pragma unroll
  for (int dy = 0; dy < 7; dy++)
    #pragma unroll
    for (int dx = 0; dx < 7; dx++)
      acc += tile[ty + dy][x + dx] * ws[dy * 7 + dx];
  out[(size_t)bc * HWp + (y0 + ty) * Wp + x] = f2b(acc);
}

// ---------------- bf16 MFMA pointwise conv (enc/dec ConvNeXt pw) ----------------
template<int CIN, int ACT, int MODE>
__global__ __launch_bounds__(256)
void pw_bf(const ushortt* __restrict__ in, const ushortt* __restrict__ wt,
           const float* __restrict__ resid, void* __restrict__ outv, int Cout) {
  int tid = threadIdx.x;
  int wid = tid >> 6, lane = tid & 63;
  int q = lane >> 4, m = lane & 15;
  int px0 = blockIdx.x * 128, co0 = blockIdx.y * 64;
  int pxh = (wid & 1) * 64, coh = (wid >> 1) * 32;
  float4v acc[4][2];
  #pragma unroll
  for (int i = 0; i < 4; i++)
    #pragma unroll
    for (int j = 0; j < 2; j++) acc[i][j] = (float4v){0.f, 0.f, 0.f, 0.f};

  #pragma unroll
  for (int k0 = 0; k0 < CIN; k0 += 32) {
    short8 a[4], b[2];
    #pragma unroll
    for (int j = 0; j < 2; j++)
      b[j] = *(const short8*)&wt[(size_t)(co0 + coh + j * 16 + m) * CIN + k0 + q * 8];
    #pragma unroll
    for (int i = 0; i < 4; i++)
      a[i] = *(const short8*)&in[(size_t)(px0 + pxh + i * 16 + m) * CIN + k0 + q * 8];
    #pragma unroll
    for (int i = 0; i < 4; i++)
      #pragma unroll
      for (int j = 0; j < 2; j++)
        acc[i][j] = __builtin_amdgcn_mfma_f32_16x16x32_bf16(a[i], b[j], acc[i][j], 0, 0, 0);
  }

  #pragma unroll
  for (int j = 0; j < 2; j++) {
    int co = co0 + coh + j * 16 + m;
    #pragma unroll
    for (int i = 0; i < 4; i++) {
      int pxb = px0 + pxh + i * 16 + q * 4;
      int bl = pxb >> 14, pim = pxb & 16383;
      if (MODE == 0) {
        #pragma unroll
        for (int r = 0; r < 4; r++) {
          float v = acc[i][j][r];
          if (ACT == 1) v = fmaxf(v, 0.f);
          ((ushortt*)outv)[(size_t)(pxb + r) * Cout + co] = f2b(v);
        }
      } else {
        float4 rr = *(const float4*)&resid[(size_t)(bl * 64 + co) * HWp + pim];
        float v0 = acc[i][j][0] + rr.x, v1 = acc[i][j][1] + rr.y;
        float v2 = acc[i][j][2] + rr.z, v3 = acc[i][j][3] + rr.w;
        if (MODE == 1) {
          ushortt* ob = (ushortt*)outv;
          ob[(size_t)(pxb + 0) * 64 + co] = f2b(v0);
          ob[(size_t)(pxb + 1) * 64 + co] = f2b(v1);
          ob[(size_t)(pxb + 2) * 64 + co] = f2b(v2);
          ob[(size_t)(pxb + 3) * 64 + co] = f2b(v3);
        } else {
          float4 w4; w4.x = v0; w4.y = v1; w4.z = v2; w4.w = v3;
          *(float4*)&((float*)outv)[(size_t)(bl * 64 + co) * HWp + pim] = w4;
        }
      }
    }
  }
}

// ---------------- plain-bf16 MFMA conv 1x1, NHWC 64ch ----------------
template<int TAPS>
__global__ __launch_bounds__(256)
void conv_bf(const ushortt* __restrict__ in, const ushortt* __restrict__ wt,
             const float* __restrict__ bias, ushortt* __restrict__ out) {
  int tid = threadIdx.x;
  int wid = tid >> 6, lane = tid & 63;
  int q = lane >> 4, m = lane & 15;
  int bx = blockIdx.x, b = blockIdx.y;
  int y = bx >> 1;
  int c0 = ((bx & 1) << 6) + ((wid & 1) << 5);
  int coW = (wid >> 1) << 5;
  size_t ibase = (size_t)b * HWp;

  float4v acc[2][2];
  #pragma unroll
  for (int i = 0; i < 2; i++)
    #pragma unroll
    for (int j = 0; j < 2; j++) acc[i][j] = (float4v){0.f, 0.f, 0.f, 0.f};
  short8 zz = {0, 0, 0, 0, 0, 0, 0, 0};

  #pragma unroll
  for (int k = 0; k < TAPS; k++) {
    int dy = (TAPS == 9) ? (k / 3 - 1) : 0;
    int dx = (TAPS == 9) ? (k % 3 - 1) : 0;
    int yy = y + dy;
    if (TAPS == 9 && (yy < 0 || yy >= Hp)) continue;
    #pragma unroll
    for (int ch = 0; ch < 2; ch++) {
      int ci0 = ch * 32 + q * 8;
      short8 bfr[2], afr[2];
      #pragma unroll
      for (int j = 0; j < 2; j++)
        bfr[j] = *(const short8*)&wt[(size_t)(k * 64 + coW + j * 16 + m) * 64 + ci0];
      #pragma unroll
      for (int i = 0; i < 2; i++) {
        int col = c0 + i * 16 + m + dx;
        bool vld = (TAPS == 1) || ((unsigned)col < (unsigned)Wp);
        int colc = min(max(col, 0), Wp - 1);
        short8 h = *(const short8*)&in[(ibase + (size_t)yy * Wp + colc) * 64 + ci0];
        afr[i] = vld ? h : zz;
      }
      #pragma unroll
      for (int i = 0; i < 2; i++)
        #pragma unroll
        for (int j = 0; j < 2; j++)
          acc[i][j] = __builtin_amdgcn_mfma_f32_16x16x32_bf16(afr[i], bfr[j], acc[i][j], 0, 0, 0);
    }
  }

  #pragma unroll
  for (int j = 0; j < 2; j++) {
    int co = coW + j * 16 + m;
    float bv = bias[co];
    #pragma unroll
    for (int i = 0; i < 2; i++) {
      #pragma unroll
      for (int r = 0; r < 4; r++) {
        size_t px = ibase + (size_t)y * Wp + c0 + i * 16 + q * 4 + r;
        float v = acc[i][j][r] + bv;
        v = v > 0.f ? v : 0.1f * v;
        out[px * 64 + co] = f2b(v);
      }
    }
  }
}

// ---------------- 3x3 pad1 NHWC 64ch conv, 2 rows/block (offset CNN) ----------------
__global__ __launch_bounds__(256)
void conv_bf9r2(const ushortt* __restrict__ in, const ushortt* __restrict__ wt,
                const float* __restrict__ bias, ushortt* __restrict__ out) {
  int tid = threadIdx.x;
  int wid = tid >> 6, lane = tid & 63;
  int q = lane >> 4, m = lane & 15;
  int bx = blockIdx.x, b = blockIdx.y;     // bx in [0,128)
  int y0 = (bx >> 1) * 2;
  int c0 = ((bx & 1) << 6) + ((wid & 1) << 5);
  int coW = (wid >> 1) << 5;
  size_t ibase = (size_t)b * HWp;

  float4v acc[2][2][2];                    // [row][i][j]
  #pragma unroll
  for (int r = 0; r < 2; r++)
    #pragma unroll
    for (int i = 0; i < 2; i++)
      #pragma unroll
      for (int j = 0; j < 2; j++) acc[r][i][j] = (float4v){0.f, 0.f, 0.f, 0.f};
  short8 zz = {0, 0, 0, 0, 0, 0, 0, 0};

  #pragma unroll
  for (int k = 0; k < 9; k++) {
    int dy = k / 3 - 1, dx = k % 3 - 1;
    #pragma unroll
    for (int ch = 0; ch < 2; ch++) {
      int ci0 = ch * 32 + q * 8;
      short8 bfr[2];
      #pragma unroll
      for (int j = 0; j < 2; j++)
        bfr[j] = *(const short8*)&wt[(size_t)(k * 64 + coW + j * 16 + m) * 64 + ci0];
      short8 afr[2][2];
      #pragma unroll
      for (int r = 0; r < 2; r++) {
        int yy = y0 + r + dy;
        bool vy = (yy >= 0 && yy < Hp);
        int yyc = min(max(yy, 0), Hp - 1);
        #pragma unroll
        for (int i = 0; i < 2; i++) {
          int col = c0 + i * 16 + m + dx;
          bool vld = vy && ((unsigned)col < (unsigned)Wp);
          int colc = min(max(col, 0), Wp - 1);
          short8 h = *(const short8*)&in[(ibase + (size_t)yyc * Wp + colc) * 64 + ci0];
          afr[r][i] = vld ? h : zz;
        }
      }
      #pragma unroll
      for (int r = 0; r < 2; r++)
        #pragma unroll
        for (int i = 0; i < 2; i++)
          #pragma unroll
          for (int j = 0; j < 2; j++)
            acc[r][i][j] = __builtin_amdgcn_mfma_f32_16x16x32_bf16(afr[r][i], bfr[j], acc[r][i][j], 0, 0, 0);
    }
  }

  #pragma unroll
  for (int j = 0; j < 2; j++) {
    int co = coW + j * 16 + m;
    float bv = bias[co];
    #pragma unroll
    for (int r = 0; r < 2; r++) {
      #pragma unroll
      for (int i = 0; i < 2; i++) {
        #pragma unroll
        for (int rr = 0; rr < 4; rr++) {
          size_t px = ibase + (size_t)(y0 + r) * Wp + c0 + i * 16 + q * 4 + rr;
          float v = acc[r][i][j][rr] + bv;
          v = v > 0.f ? v : 0.1f * v;
          out[px * 64 + co] = f2b(v);
        }
      }
    }
  }
}

// ---------------- NCHW bf16 -> NHWC bf16 transpose (full batch) ----------------
__global__ __launch_bounds__(256)
void t64b(const ushortt* __restrict__ in, ushortt* __restrict__ out) {
  __shared__ ushortt tl[64 * 65];
  int tid = threadIdx.x;
  int b = blockIdx.y;
  int px0 = blockIdx.x * 64;
  int lpx = tid & 63, c4 = tid >> 6;
  const ushortt* ip = in + (size_t)b * 64 * HWp;
  #pragma unroll
  for (int i = 0; i < 16; i++) {
    int c = c4 + 4 * i;
    tl[lpx * 65 + c] = ip[(size_t)c * HWp + px0 + lpx];
  }
  __syncthreads();
  int ci = tid & 63, pr = tid >> 6;
  #pragma unroll
  for (int i = 0; i < 16; i++) {
    int r = pr + 4 * i;
    out[((size_t)b * HWp + px0 + r) * 64 + ci] = tl[r * 65 + ci];
  }
}

// ---------------- merged weight repack (all segments, 5245 blocks) ----------------
__global__ __launch_bounds__(256)
void repack_all(const float* __restrict__ w1a, const float* __restrict__ w3a,
                const float* __restrict__ w5a, const float* __restrict__ inv2,
                const float* __restrict__ d2, const float* __restrict__ d4,
                const float* __restrict__ d6, const float* __restrict__ ow1,
                const float* __restrict__ ow2, const float* __restrict__ ow3,
                const float* __restrict__ ow4, const float* __restrict__ ow5,
                const float* __restrict__ p1, const float* __restrict__ p2,
                const float* __restrict__ p3, const float* __restrict__ p4,
                ushortt* __restrict__ wb, ushortt* __restrict__ wbi2,
                ushortt* __restrict__ wdwb, ushortt* __restrict__ wc1,
                ushortt* __restrict__ wc2, ushortt* __restrict__ wpw) {
  int b = blockIdx.x;
  int tid = threadIdx.x;
  if (b < 4320) {                       // wie_w1/3/5 -> wb (640-padded, perm)
    int which = b / 1440;
    int idx = (b - which * 1440) * 256 + tid;
    const float* in = which == 0 ? w1a : which == 1 ? w3a : w5a;
    int cop = idx / 576, cip = idx % 576;
    ushortt v = 0;
    if (cop < 576) {
      int co = (cop & 63) * 9 + (cop >> 6);
      int ci = (cip & 63) * 9 + (cip >> 6);
      v = f2b(in[(size_t)co * 576 + ci]);
    }
    wb[(size_t)which * 640 * 576 + idx] = v;
  } else if (b < 4464) {                // inv_w2 -> wbi2
    int idx = (b - 4320) * 256 + tid;
    if (idx < 64 * 576) {
      int co = idx / 576, cip = idx % 576;
      int ci = (cip & 63) * 9 + (cip >> 6);
      wbi2[idx] = f2b(inv2[(size_t)co * 576 + ci]);
    }
  } else if (b < 4525) {                // wie_w2/4/6 dw -> wdwb
    int idx = (b - 4464) * 256 + tid;
    if (idx < 3 * 5184) {
      int which = idx / 5184, r = idx % 5184;
      const float* in = which == 0 ? d2 : which == 1 ? d4 : d6;
      int tap = r / 576, chp = r % 576;
      int ch = (chp & 63) * 9 + (chp >> 6);
      wdwb[idx] = f2b(in[ch * 9 + tap]);
    }
  } else if (b < 4541) {                // off_w1 -> wc1
    int idx = (b - 4525) * 256 + tid;
    if (idx < 4096) wc1[idx] = f2b(ow1[idx]);
  } else if (b < 5117) {                // off_w2..5 -> wc2
    int bb = b - 4541;
    int which = bb / 144;
    int idx = (bb - which * 144) * 256 + tid;
    if (idx < 36864) {
      const float* in = which == 0 ? ow2 : which == 1 ? ow3 : which == 2 ? ow4 : ow5;
      int k = idx >> 12, r = idx & 4095;
      int co = r >> 6, ci = r & 63;
      wc2[which * 36864 + idx] = f2b(in[(size_t)(co * 64 + ci) * 9 + k]);
    }
  } else {                              // enc/dec pw -> wpw
    int bb = b - 5117;
    int which = bb / 32;
    int idx = (bb - which * 32) * 256 + tid;
    if (idx < 8192) {
      const float* in = which == 0 ? p1 : which == 1 ? p2 : which == 2 ? p3 : p4;
      wpw[which * 8192 + idx] = f2b(in[idx]);
    }
  }
}

// ---------------- off_w6 -> NCHW offsets, 8*tanh ----------------
__global__ __launch_bounds__(256)
void off6_nhwc(const ushortt* __restrict__ hi, const float* __restrict__ wgt,
               const float* __restrict__ bias, float* __restrict__ out) {
  __shared__ float Wl[18 * 64];
  for (int i = threadIdx.x; i < 18 * 64; i += 256) Wl[i] = wgt[i];
  __syncthreads();
  int px = blockIdx.x * 256 + threadIdx.x;
  int b = px >> 14, pim = px & 16383;
  float acc[18];
  #pragma unroll
  for (int j = 0; j < 18; j++) acc[j] = 0.f;
  const uint4* ph = (const uint4*)(hi + (size_t)px * 64);
  for (int g = 0; g < 8; g++) {
    uint4 H = ph[g];
    u32 hw[4] = {H.x, H.y, H.z, H.w};
    #pragma unroll
    for (int t = 0; t < 4; t++) {
      float v0 = blo(hw[t]);
      float v1 = bhi(hw[t]);
      int ci = g * 8 + t * 2;
      #pragma unroll
      for (int j = 0; j < 18; j++)
        acc[j] += Wl[j * 64 + ci] * v0 + Wl[j * 64 + ci + 1] * v1;
    }
  }
  #pragma unroll
  for (int j = 0; j < 18; j++)
    out[((size_t)b * 18 + j) * HWp + pim] = 8.f * tanhf(acc[j] + bias[j]);
}

// ---------------- deform v2: 4ch/lane uint2 gathers, 4px/wave, XCD row-aligned ----------------
__global__ __launch_bounds__(256)
void deform_x(const ushortt* __restrict__ xn0, const float* __restrict__ offs0,
              ushortt* __restrict__ xb) {
  int lin = blockIdx.x;
  int xcd = lin & 7, local = lin >> 3;    // [0,256)
  int rowi = local >> 3, bx = local & 7;
  int tid = threadIdx.x;
  int wid = tid >> 6, lane = tid & 63;
  int c4 = lane & 15, ps = lane >> 4;     // 16 lanes/px, 4 ch/lane; 4 px/wave
  int pg = (xcd * 32 + rowi) * 128 + bx * 16 + wid * 4 + ps;
  int bl = pg >> 14, p = pg & 16383;
  const ushortt* xn = xn0 + (size_t)bl * HWp * 64;
  const float* offs = offs0 + (size_t)bl * 18 * HWp;
  int yi = p >> 7, xi = p & 127;
  #pragma unroll
  for (int k = 0; k < 9; k++) {
    float dy = offs[(size_t)(2 * k) * HWp + p];
    float dx = offs[(size_t)(2 * k + 1) * HWp + p];
    float py = (float)yi + (float)(k / 3 - 1) + dy;
    float px = (float)xi + (float)(k % 3 - 1) + dx;
    float y0f = floorf(py), x0f = floorf(px);
    float wy1 = py - y0f, wy0 = 1.f - wy1;
    float wx1 = px - x0f, wx0 = 1.f - wx1;
    int y0 = (int)y0f, x0 = (int)x0f;
    bool vy0 = (y0 >= 0 && y0 < Hp), vy1 = (y0 + 1 >= 0 && y0 + 1 < Hp);
    bool vx0 = (x0 >= 0 && x0 < Wp), vx1 = (x0 + 1 >= 0 && x0 + 1 < Wp);
    int yc0 = min(max(y0, 0), Hp - 1), yc1 = min(max(y0 + 1, 0), Hp - 1);
    int xc0 = min(max(x0, 0), Wp - 1), xc1 = min(max(x0 + 1, 0), Wp - 1);
    float w00 = wy0 * wx0 * ((vy0 && vx0) ? 1.f : 0.f);
    float w01 = wy0 * wx1 * ((vy0 && vx1) ? 1.f : 0.f);
    float w10 = wy1 * wx0 * ((vy1 && vx0) ? 1.f : 0.f);
    float w11 = wy1 * wx1 * ((vy1 && vx1) ? 1.f : 0.f);
    uint2 t00 = *(const uint2*)&xn[(size_t)(yc0 * Wp + xc0) * 64 + c4 * 4];
    uint2 t01 = *(const uint2*)&xn[(size_t)(yc0 * Wp + xc1) * 64 + c4 * 4];
    uint2 t10 = *(const uint2*)&xn[(size_t)(yc1 * Wp + xc0) * 64 + c4 * 4];
    uint2 t11 = *(const uint2*)&xn[(size_t)(yc1 * Wp + xc1) * 64 + c4 * 4];
    float a0 = blo(t00.x) * w00 + blo(t01.x) * w01 + blo(t10.x) * w10 + blo(t11.x) * w11;
    float b0 = bhi(t00.x) * w00 + bhi(t01.x) * w01 + bhi(t10.x) * w10 + bhi(t11.x) * w11;
    float a1 = blo(t00.y) * w00 + blo(t01.y) * w01 + blo(t10.y) * w10 + blo(t11.y) * w11;
    float b1 = bhi(t00.y) * w00 + bhi(t01.y) * w01 + bhi(t10.y) * w10 + bhi(t11.y) * w11;
    uint2 st;
    st.x = (u32)f2b(a0) | (((u32)f2b(b0)) << 16);
    st.y = (u32)f2b(a1) | (((u32)f2b(b1)) << 16);
    *(uint2*)&xb[(size_t)pg * 576 + 64 * k + c4 * 4] = st;
  }
}

// ---------------- MFMA bf16 GEMM, 128x128 tile, XCD-partitioned ----------------
// v2 (measured best): 2-phase double-buffered LDS + swapped-operand coalesced
// epilogue. v3/v4/v5 all regressed -> this is the structure's floor.
__global__ __launch_bounds__(256)
void gemm128(const ushortt* __restrict__ X, const ushortt* __restrict__ Wb,
             ushortt* __restrict__ out) {
  __shared__ ushortt Xs[2][4096];
  __shared__ ushortt Wsh[2][4096];
  int tid = threadIdx.x;
  int lin = blockIdx.x + blockIdx.y * 5;
  int xcd = lin & 7, loc = lin >> 3;
  int co_t = loc % 5;
  int px_t = xcd * 32 + loc / 5;
  int co0 = co_t * 128, px0 = px_t * 128;
  int r0 = tid >> 2;
  int sch = (tid & 3) ^ ((tid >> 3) & 3);
  size_t gx0 = (size_t)(px0 + r0) * 576 + sch * 8;
  size_t gx1 = gx0 + (size_t)64 * 576;
  size_t gw0 = (size_t)(co0 + r0) * 576 + sch * 8;
  size_t gw1 = gw0 + (size_t)64 * 576;
  int wid = tid >> 6, lane = tid & 63;
  int q = lane >> 4, m = lane & 15;
  int qx = (q ^ ((m >> 1) & 3)) * 8;
  int pxh = (wid & 1) * 64, coh = (wid >> 1) * 64;
  float4v acc[4][4];
  #pragma unroll
  for (int i = 0; i < 4; i++)
    #pragma unroll
    for (int j = 0; j < 4; j++) acc[i][j] = (float4v){0.f, 0.f, 0.f, 0.f};

  // prologue: stage K-step 0 into buffer 0
  gll(X + gx0,  &Xs[0][tid * 8]);
  gll(X + gx1,  &Xs[0][2048 + tid * 8]);
  gll(Wb + gw0, &Wsh[0][tid * 8]);
  gll(Wb + gw1, &Wsh[0][2048 + tid * 8]);
  __syncthreads();

  int cur = 0;
  for (int k0 = 0; k0 < 576; k0 += 32) {
    if (k0 + 32 < 576) {               // prefetch next K-step into other buffer
      gll(X + gx0 + k0 + 32,  &Xs[cur ^ 1][tid * 8]);
      gll(X + gx1 + k0 + 32,  &Xs[cur ^ 1][2048 + tid * 8]);
      gll(Wb + gw0 + k0 + 32, &Wsh[cur ^ 1][tid * 8]);
      gll(Wb + gw1 + k0 + 32, &Wsh[cur ^ 1][2048 + tid * 8]);
    }
    short8 a[4], b[4];
    #pragma unroll
    for (int i = 0; i < 4; i++)
      a[i] = *(const short8*)&Xs[cur][(pxh + i * 16 + m) * 32 + qx];
    #pragma unroll
    for (int j = 0; j < 4; j++)
      b[j] = *(const short8*)&Wsh[cur][(coh + j * 16 + m) * 32 + qx];
    #pragma unroll
    for (int i = 0; i < 4; i++)
      #pragma unroll
      for (int j = 0; j < 4; j++)
        acc[i][j] = __builtin_amdgcn_mfma_f32_16x16x32_bf16(b[j], a[i], acc[i][j], 0, 0, 0);
    __syncthreads();                   // drains prefetch (vmcnt0) + LDS reads
    cur ^= 1;
  }

  // epilogue: swapped orientation -> reg index r runs along co (contiguous)
  #pragma unroll
  for (int j = 0; j < 4; j++) {
    int cob = co0 + coh + j * 16 + q * 4;
    if (cob >= 576) continue;
    #pragma unroll
    for (int i = 0; i < 4; i++) {
      size_t px = (size_t)(px0 + pxh + i * 16 + m);
      u32 lo = (u32)f2b(acc[i][j][0]) | (((u32)f2b(acc[i][j][1])) << 16);
      u32 hi = (u32)f2b(acc[i][j][2]) | (((u32)f2b(acc[i][j][3])) << 16);
      uint2 st; st.x = lo; st.y = hi;
      *(uint2*)&out[px * 576 + cob] = st;
    }
  }
}

// ---------------- MFMA bf16 GEMM 576->64 (inv2), out fp32 NCHW, XCD row-aligned ----------------
// v2: 2-phase double-buffered K-loop (verified transformation).
__global__ __launch_bounds__(256)
void gemm64o2(const ushortt* __restrict__ X, const ushortt* __restrict__ Wb,
              float* __restrict__ outv) {
  __shared__ ushortt Xs[2][4096];
  __shared__ ushortt Wsh[2][2048];
  int tid = threadIdx.x;
  int lin = blockIdx.x;
  int xcd = lin & 7, local = lin >> 3;      // [0,32)
  int px0 = (xcd * 32 + local) * 128;
  int srow = tid >> 2;
  int sch = (tid & 3) ^ ((tid >> 3) & 3);
  size_t gxo0 = (size_t)(px0 + srow) * 576 + sch * 8;
  size_t gxo1 = gxo0 + (size_t)64 * 576;
  size_t gwo  = (size_t)srow * 576 + sch * 8;
  int wid = tid >> 6, lane = tid & 63;
  int q = lane >> 4, m = lane & 15;
  int qx = (q ^ ((m >> 1) & 3)) * 8;
  int pxh = (wid & 1) * 64, coh = (wid >> 1) * 32;
  float4v acc[4][2];
  #pragma unroll
  for (int i = 0; i < 4; i++)
    #pragma unroll
    for (int j = 0; j < 2; j++) acc[i][j] = (float4v){0.f, 0.f, 0.f, 0.f};

  // prologue: stage K-step 0 into buffer 0
  gll(X + gxo0,  &Xs[0][tid * 8]);
  gll(X + gxo1,  &Xs[0][2048 + tid * 8]);
  gll(Wb + gwo,  &Wsh[0][tid * 8]);
  __syncthreads();

  int cur = 0;
  for (int k0 = 0; k0 < 576; k0 += 32) {
    if (k0 + 32 < 576) {               // prefetch next K-step into other buffer
      gll(X + gxo0 + k0 + 32,  &Xs[cur ^ 1][tid * 8]);
      gll(X + gxo1 + k0 + 32,  &Xs[cur ^ 1][2048 + tid * 8]);
      gll(Wb + gwo + k0 + 32,  &Wsh[cur ^ 1][tid * 8]);
    }
    short8 a[4], b[2];
    #pragma unroll
    for (int i = 0; i < 4; i++)
      a[i] = *(const short8*)&Xs[cur][(pxh + i * 16 + m) * 32 + qx];
    #pragma unroll
    for (int j = 0; j < 2; j++)
      b[j] = *(const short8*)&Wsh[cur][(coh + j * 16 + m) * 32 + qx];
    #pragma unroll
    for (int i = 0; i < 4; i++)
      #pragma unroll
      for (int j = 0; j < 2; j++)
        acc[i][j] = __builtin_amdgcn_mfma_f32_16x16x32_bf16(a[i], b[j], acc[i][j], 0, 0, 0);
    __syncthreads();                   // drains prefetch + LDS reads
    cur ^= 1;
  }

  #pragma unroll
  for (int j = 0; j < 2; j++) {
    int co = coh + j * 16 + m;
    #pragma unroll
    for (int i = 0; i < 4; i++) {
      int pxb = px0 + pxh + i * 16 + q * 4;
      int bl = pxb >> 14, pim = pxb & 16383;
      float4 r;
      r.x = acc[i][j][0]; r.y = acc[i][j][1];
      r.z = acc[i][j][2]; r.w = acc[i][j][3];
      *(float4*)&outv[(size_t)(bl * 64 + co) * HWp + pim] = r;
    }
  }
}

// ---------------- depthwise 3x3 NHWC bf16 v3: XCD row-aligned, 8ch x 4 rows ----------------
template<int ACT>
__global__ __launch_bounds__(256)
void dw3x3_v3(const ushortt* __restrict__ in, const ushortt* __restrict__ wt,
              ushortt* __restrict__ out) {
  int lin = blockIdx.x;
  int xcd = lin & 7, local = lin >> 3;     // [0,344)
  int g = local / 43, bxq = local - g * 43;
  int rg = xcd * 8 + g;                    // combined row-group [0,64)
  int bz = rg >> 5, by = rg & 31;
  int tid = threadIdx.x;
  int pxl = tid / 72;
  int gg = tid - pxl * 72;
  if (pxl >= 3) return;
  int x = bxq * 3 + pxl;
  if (x >= Wp) return;
  int y0 = by * 4;
  size_t bbase = (size_t)bz * HWp;

  float w[9][8];
  #pragma unroll
  for (int t = 0; t < 9; t++) {
    uint4 wv = *(const uint4*)&wt[t * 576 + gg * 8];
    u32 wsw[4] = {wv.x, wv.y, wv.z, wv.w};
    #pragma unroll
    for (int p = 0; p < 4; p++) {
      w[t][2 * p]     = blo(wsw[p]);
      w[t][2 * p + 1] = bhi(wsw[p]);
    }
  }
  float acc[4][8];
  #pragma unroll
  for (int o = 0; o < 4; o++)
    #pragma unroll
    for (int c = 0; c < 8; c++) acc[o][c] = 0.f;

  #pragma unroll
  for (int ri = 0; ri < 6; ri++) {
    int yy = y0 - 1 + ri;
    bool vr = (yy >= 0 && yy < Hp);
    float v[3][8];
    #pragma unroll
    for (int dx = 0; dx < 3; dx++) {
      int xx = x + dx - 1;
      uint4 t4 = {0, 0, 0, 0};
      if (vr && xx >= 0 && xx < Wp)
        t4 = *(const uint4*)&in[(bbase + (size_t)yy * Wp + xx) * 576 + gg * 8];
      u32 tw[4] = {t4.x, t4.y, t4.z, t4.w};
      #pragma unroll
      for (int p = 0; p < 4; p++) {
        v[dx][2 * p]     = blo(tw[p]);
        v[dx][2 * p + 1] = bhi(tw[p]);
      }
    }
    #pragma unroll
    for (int o = 0; o < 4; o++) {
      int dy = ri - o;
      if (dy < 0 || dy > 2) continue;
      #pragma unroll
      for (int dx = 0; dx < 3; dx++)
        #pragma unroll
        for (int c = 0; c < 8; c++)
          acc[o][c] += w[dy * 3 + dx][c] * v[dx][c];
    }
  }

  #pragma unroll
  for (int o = 0; o < 4; o++) {
    int yy = y0 + o;
    u32 pk[4];
    #pragma unroll
    for (int p = 0; p < 4; p++) {
      float r0 = acc[o][2 * p], r1 = acc[o][2 * p + 1];
      if (ACT == 1) { r0 = fmaxf(r0, 0.f); r1 = fmaxf(r1, 0.f); }
      else { r0 = 1.f / (1.f + __expf(-r0)); r1 = 1.f / (1.f + __expf(-r1)); }
      pk[p] = (u32)f2b(r0) | (((u32)f2b(r1)) << 16);
    }
    uint4 o4; o4.x = pk[0]; o4.y = pk[1]; o4.z = pk[2]; o4.w = pk[3];
    *(uint4*)&out[(bbase + (size_t)yy * Wp + x) * 576 + gg * 8] = o4;
  }
}

// ---------------- g9inv2 v3: dct-from-xb + wiener mul + inv1, 2ch/lane packed ----------------
// Thread = (2 channels x 2 px) via u32 loads/stores (was 1 ch x 4 px scalar):
// half the VMEM instructions, same per-(px,c) math and order -> bit-identical.
__global__ __launch_bounds__(256)
void g9inv2(const ushortt* __restrict__ wien, const ushortt* __restrict__ xb,
            const float* __restrict__ wdct, const float* __restrict__ winv,
            ushortt* __restrict__ outb) {
  __shared__ float Wd[5184];
  __shared__ float Wi[5184];
  for (int i = threadIdx.x; i < 5184; i += 256) {
    Wd[i] = wdct[i];
    Wi[i] = winv[i];
  }
  __syncthreads();
  int lin = blockIdx.x;
  int xcd = lin & 7, local = lin >> 3;     // [0,256)
  int rowi = local >> 3, bx = local & 7;
  int pslot = threadIdx.x >> 5;            // [0,8): 2 px each
  int c2 = threadIdx.x & 31;               // channels 2*c2, 2*c2+1
  size_t px0 = (size_t)((xcd * 32 + rowi) * 128 + bx * 16 + pslot * 2);
  const float* wd0 = &Wd[(2 * c2) * 81];
  const float* wd1 = &Wd[(2 * c2 + 1) * 81];
  const float* wi0 = &Wi[(2 * c2) * 81];
  const float* wi1 = &Wi[(2 * c2 + 1) * 81];

  float xr[2][9][2];                       // [px][tap][ch]
  #pragma unroll
  for (int u = 0; u < 2; u++)
    #pragma unroll
    for (int t = 0; t < 9; t++) {
      u32 xv = *(const u32*)&xb[(px0 + u) * 576 + 64 * t + c2 * 2];
      xr[u][t][0] = blo(xv);
      xr[u][t][1] = bhi(xv);
    }

  float wv[2][9][2];
  #pragma unroll
  for (int u = 0; u < 2; u++)
    #pragma unroll
    for (int o = 0; o < 9; o++) {
      u32 wvv = *(const u32*)&wien[(px0 + u) * 576 + 64 * o + c2 * 2];
      wv[u][o][0] = blo(wvv);
      wv[u][o][1] = bhi(wvv);
    }

  float v[2][9][2];
  #pragma unroll
  for (int o = 0; o < 9; o++) {
    #pragma unroll
    for (int u = 0; u < 2; u++) {
      float d0 = 0.f, d1 = 0.f;
      #pragma unroll
      for (int t = 0; t < 9; t++) {
        d0 += wd0[o * 9 + t] * xr[u][t][0];
        d1 += wd1[o * 9 + t] * xr[u][t][1];
      }
      v[u][o][0] = wv[u][o][0] * d0;
      v[u][o][1] = wv[u][o][1] * d1;
    }
  }
  #pragma unroll
  for (int j = 0; j < 9; j++) {
    #pragma unroll
    for (int u = 0; u < 2; u++) {
      float a0 = 0.f, a1 = 0.f;
      #pragma unroll
      for (int o = 0; o < 9; o++) {
        a0 += wi0[j * 9 + o] * v[u][o][0];
        a1 += wi1[j * 9 + o] * v[u][o][1];
      }
      u32 st = (u32)f2b(a0) | (((u32)f2b(a1)) << 16);
      *(u32*)&outb[(px0 + u) * 576 + 64 * j + c2 * 2] = st;
    }
  }
}

// ---------------- launch ----------------
extern "C" void kernel_launch(void* const* d_in, const int* in_sizes, int n_in,
                              void* d_out, int out_size, void* d_ws, size_t ws_size,
                              hipStream_t stream) {
  const float* x       = (const float*)d_in[0];
  const float* enc_dw  = (const float*)d_in[1];
  const float* enc_pw1 = (const float*)d_in[2];
  const float* enc_pw2 = (const float*)d_in[3];
  const float* dec_dw  = (const float*)d_in[4];
  const float* dec_pw1 = (const float*)d_in[5];
  const float* dec_pw2 = (const float*)d_in[6];
  const float* off_w1  = (const float*)d_in[7];
  const float* off_b1  = (const float*)d_in[8];
  const float* off_w2  = (const float*)d_in[9];
  const float* off_b2  = (const float*)d_in[10];
  const float* off_w3  = (const float*)d_in[11];
  const float* off_b3  = (const float*)d_in[12];
  const float* off_w4  = (const float*)d_in[13];
  const float* off_b4  = (const float*)d_in[14];
  const float* off_w5  = (const float*)d_in[15];
  const float* off_b5  = (const float*)d_in[16];
  const float* off_w6  = (const float*)d_in[17];
  const float* off_b6  = (const float*)d_in[18];
  const float* dct_w   = (const float*)d_in[19];
  const float* wie_w1  = (const float*)d_in[20];
  const float* wie_w2  = (const float*)d_in[21];
  const float* wie_w3  = (const float*)d_in[22];
  const float* wie_w4  = (const float*)d_in[23];
  const float* wie_w5  = (const float*)d_in[24];
  const float* wie_w6  = (const float*)d_in[25];
  const float* inv_w1  = (const float*)d_in[26];
  const float* inv_w2  = (const float*)d_in[27];
  float* outp = (float*)d_out;

  const size_t NP = (size_t)Bp * HWp;
  const size_t REQ_FLOATS = NP * 64 + NP * 64 + NP * 128 +
                            2 * (size_t)HWp * CKp + (size_t)HWp * CKp;
  if (ws_size < REQ_FLOATS * sizeof(float)) return;

  float* ws  = (float*)d_ws;
  float* x1  = ws;
  float* t0  = x1 + NP * 64;
  float* t1  = t0 + NP * 64;
  float* bigA = t1 + NP * 128;
  float* bigB = bigA + (size_t)HWp * CKp;
  float* bigC = bigB + (size_t)HWp * CKp;
  ushortt* R1 = (ushortt*)bigA;
  ushortt* R2 = (ushortt*)bigB;
  ushortt* R3 = (ushortt*)bigC;
  ushortt* e1 = (ushortt*)bigA;

  float* wreg = t0 + NP * 18;
  ushortt* wb  = (ushortt*)wreg;
  ushortt* wbi2 = wb + 3 * 640 * 576;
  ushortt* wdwb = wbi2 + 64 * 576;
  ushortt* wc1  = wdwb + 3 * 5184;
  ushortt* wc2  = wc1 + 4096;
  ushortt* wpw  = wc2 + 4 * 36864;

  ushortt* xnAll = (ushortt*)t1;
  ushortt* oA = xnAll + NP * 64;
  ushortt* oB = oA + NP * 64;

  float* offs = t0;
  float* mid  = x1;

  dim3 blk(256);

  // ---- enc ConvNeXt: dw7 fp32->bf16, pw via bf16 MFMA ----
  dwconv7_lds<<<dim3(Hp / 2, Bp * Cp), blk, 0, stream>>>(x, enc_dw, (ushortt*)t0);
  t64b<<<dim3(HWp / 64, Bp), blk, 0, stream>>>((const ushortt*)t0, oA);

  // ---- merged weight repack ----
  repack_all<<<dim3(5245), blk, 0, stream>>>(
      wie_w1, wie_w3, wie_w5, inv_w2, wie_w2, wie_w4, wie_w6, off_w1,
      off_w2, off_w3, off_w4, off_w5, enc_pw1, enc_pw2, dec_pw1, dec_pw2,
      wb, wbi2, wdwb, wc1, wc2, wpw);

  pw_bf<64, 1, 0><<<dim3(NP / 128, 2), blk, 0, stream>>>(oA, wpw, nullptr, e1, 128);
  pw_bf<128, 0, 1><<<dim3(NP / 128, 1), blk, 0, stream>>>(e1, wpw + 8192, x, xnAll, 64);

  // ---- offset CNN (full batch, bf16 MFMA, NHWC; 3x3 layers 2-row) ----
  conv_bf<1><<<dim3(HWp / 64, Bp), blk, 0, stream>>>(xnAll, wc1, off_b1, oA);
  conv_bf9r2<<<dim3(128, Bp), blk, 0, stream>>>(oA, wc2,             off_b2, oB);
  conv_bf9r2<<<dim3(128, Bp), blk, 0, stream>>>(oB, wc2 + 36864,     off_b3, oA);
  conv_bf9r2<<<dim3(128, Bp), blk, 0, stream>>>(oA, wc2 + 2 * 36864, off_b4, oB);
  conv_bf9r2<<<dim3(128, Bp), blk, 0, stream>>>(oB, wc2 + 3 * 36864, off_b5, oA);
  off6_nhwc<<<dim3(NP / 256), blk, 0, stream>>>(oA, off_w6, off_b6, offs);

  // ---- 576-channel middle: 2 batches per pass; xb persists in R2 ----
  for (int bp = 0; bp < 2; bp++) {
    const ushortt* xn0 = xnAll + (size_t)(2 * bp) * HWp * 64;
    const float* off0 = offs + (size_t)(2 * bp) * 18 * HWp;
    float* mid0 = mid + (size_t)(2 * bp) * 64 * HWp;

    deform_x<<<dim3(2048), blk, 0, stream>>>(xn0, off0, R2);
    gemm128<<<dim3(5, 256), blk, 0, stream>>>(R2, wb, R3);
    dw3x3_v3<1><<<dim3(2752), blk, 0, stream>>>(R3, wdwb, R1);
    gemm128<<<dim3(5, 256), blk, 0, stream>>>(R1, wb + 640 * 576, R3);
    dw3x3_v3<1><<<dim3(2752), blk, 0, stream>>>(R3, wdwb + 5184, R1);
    gemm128<<<dim3(5, 256), blk, 0, stream>>>(R1, wb + 2 * 640 * 576, R3);
    dw3x3_v3<2><<<dim3(2752), blk, 0, stream>>>(R3, wdwb + 2 * 5184, R1);  // wiener
    g9inv2<<<dim3(2048), blk, 0, stream>>>(R1, R2, dct_w, inv_w1, R3);
    gemm64o2<<<dim3(256), blk, 0, stream>>>(R3, wbi2, mid0);
  }

  // ---- dec ConvNeXt: dw7 fp32->bf16 (tmp in bigB), pw via bf16 MFMA ----
  dwconv7_lds<<<dim3(Hp / 2, Bp * Cp), blk, 0, stream>>>(mid, dec_dw, (ushortt*)bigB);
  t64b<<<dim3(HWp / 64, Bp), blk, 0, stream>>>((const ushortt*)bigB, oA);
  pw_bf<64, 1, 0><<<dim3(NP / 128, 2), blk, 0, stream>>>(oA, wpw + 2 * 8192, nullptr, e1, 128);
  pw_bf<128, 0, 2><<<dim3(NP / 128, 1), blk, 0, stream>>>(e1, wpw + 3 * 8192, mid, outp, 64);
}

// Round 18
// 835.984 us; speedup vs baseline: 1.0175x; 1.0175x over previous
//
#include <hip/hip_runtime.h>
#include <math.h>

#define HWp 16384
#define Wp 128
#define Hp 128
#define Bp 4
#define Cp 64
#define CKp 576

typedef unsigned int u32;
typedef unsigned short ushortt;
typedef __attribute__((ext_vector_type(8))) short short8;
typedef __attribute__((ext_vector_type(4))) float float4v;

__device__ __forceinline__ ushortt f2b(float f) {
  union { float f; u32 u; } x; x.f = f;
  u32 r = x.u + 0x7fff + ((x.u >> 16) & 1);
  return (ushortt)(r >> 16);
}
__device__ __forceinline__ float b2f(ushortt h) {
  union { u32 u; float f; } x; x.u = ((u32)h) << 16; return x.f;
}
__device__ __forceinline__ float blo(u32 t) {
  union { u32 u; float f; } x; x.u = t << 16; return x.f;
}
__device__ __forceinline__ float bhi(u32 t) {
  union { u32 u; float f; } x; x.u = t & 0xffff0000u; return x.f;
}
__device__ __forceinline__ void gll(const ushortt* g, ushortt* l) {
  __builtin_amdgcn_global_load_lds(
      (const __attribute__((address_space(1))) u32*)g,
      (__attribute__((address_space(3))) u32*)l, 16, 0, 0);
}

// ---------------- depthwise 7x7, pad 3, LDS-tiled (NCHW in, bf16 NCHW out) ----------------
__global__ __launch_bounds__(256)
void dwconv7_lds(const float* __restrict__ in, const float* __restrict__ w,
                 ushortt* __restrict__ out) {
  int bc = blockIdx.y;
  int tid = threadIdx.x;
  int y0 = blockIdx.x * 2;
  __shared__ float ws[49];
  __shared__ float tile[8][136];
  if (tid < 49) ws[tid] = w[(bc & 63) * 49 + tid];
  if (tid < 48) {
    int r = tid / 6, cc = tid % 6;
    tile[r][cc < 3 ? cc : 128 + cc] = 0.f;
  }
  const float* ip = in + (size_t)bc * HWp;
  #pragma unroll
  for (int i = 0; i < 4; i++) {
    int idx = tid + 256 * i;
    int r = idx >> 7, xx = idx & 127;
    int yy = y0 - 3 + r;
    tile[r][xx + 3] = (yy >= 0 && yy < Hp) ? ip[yy * Wp + xx] : 0.f;
  }
  __syncthreads();
  int ty = tid >> 7, x = tid & 127;
  float acc = 0.f;
  #pragma unroll
  for (int dy = 0; dy < 7; dy++)
    #pragma unroll
    for (int dx = 0; dx < 7; dx++)
      acc += tile[ty + dy][x + dx] * ws[dy * 7 + dx];
  out[(size_t)bc * HWp + (y0 + ty) * Wp + x] = f2b(acc);
}

// ---------------- bf16 MFMA pointwise conv (enc/dec ConvNeXt pw) ----------------
template<int CIN, int ACT, int MODE>
__global__ __launch_bounds__(256)
void pw_bf(const ushortt* __restrict__ in, const ushortt* __restrict__ wt,
           const float* __restrict__ resid, void* __restrict__ outv, int Cout) {
  int tid = threadIdx.x;
  int wid = tid >> 6, lane = tid & 63;
  int q = lane >> 4, m = lane & 15;
  int px0 = blockIdx.x * 128, co0 = blockIdx.y * 64;
  int pxh = (wid & 1) * 64, coh = (wid >> 1) * 32;
  float4v acc[4][2];
  #pragma unroll
  for (int i = 0; i < 4; i++)
    #pragma unroll
    for (int j = 0; j < 2; j++) acc[i][j] = (float4v){0.f, 0.f, 0.f, 0.f};

  #pragma unroll
  for (int k0 = 0; k0 < CIN; k0 += 32) {
    short8 a[4], b[2];
    #pragma unroll
    for (int j = 0; j < 2; j++)
      b[j] = *(const short8*)&wt[(size_t)(co0 + coh + j * 16 + m) * CIN + k0 + q * 8];
    #pragma unroll
    for (int i = 0; i < 4; i++)
      a[i] = *(const short8*)&in[(size_t)(px0 + pxh + i * 16 + m) * CIN + k0 + q * 8];
    #pragma unroll
    for (int i = 0; i < 4; i++)
      #pragma unroll
      for (int j = 0; j < 2; j++)
        acc[i][j] = __builtin_amdgcn_mfma_f32_16x16x32_bf16(a[i], b[j], acc[i][j], 0, 0, 0);
  }

  #pragma unroll
  for (int j = 0; j < 2; j++) {
    int co = co0 + coh + j * 16 + m;
    #pragma unroll
    for (int i = 0; i < 4; i++) {
      int pxb = px0 + pxh + i * 16 + q * 4;
      int bl = pxb >> 14, pim = pxb & 16383;
      if (MODE == 0) {
        #pragma unroll
        for (int r = 0; r < 4; r++) {
          float v = acc[i][j][r];
          if (ACT == 1) v = fmaxf(v, 0.f);
          ((ushortt*)outv)[(size_t)(pxb + r) * Cout + co] = f2b(v);
        }
      } else {
        float4 rr = *(const float4*)&resid[(size_t)(bl * 64 + co) * HWp + pim];
        float v0 = acc[i][j][0] + rr.x, v1 = acc[i][j][1] + rr.y;
        float v2 = acc[i][j][2] + rr.z, v3 = acc[i][j][3] + rr.w;
        if (MODE == 1) {
          ushortt* ob = (ushortt*)outv;
          ob[(size_t)(pxb + 0) * 64 + co] = f2b(v0);
          ob[(size_t)(pxb + 1) * 64 + co] = f2b(v1);
          ob[(size_t)(pxb + 2) * 64 + co] = f2b(v2);
          ob[(size_t)(pxb + 3) * 64 + co] = f2b(v3);
        } else {
          float4 w4; w4.x = v0; w4.y = v1; w4.z = v2; w4.w = v3;
          *(float4*)&((float*)outv)[(size_t)(bl * 64 + co) * HWp + pim] = w4;
        }
      }
    }
  }
}

// ---------------- plain-bf16 MFMA conv 1x1, NHWC 64ch ----------------
template<int TAPS>
__global__ __launch_bounds__(256)
void conv_bf(const ushortt* __restrict__ in, const ushortt* __restrict__ wt,
             const float* __restrict__ bias, ushortt* __restrict__ out) {
  int tid = threadIdx.x;
  int wid = tid >> 6, lane = tid & 63;
  int q = lane >> 4, m = lane & 15;
  int bx = blockIdx.x, b = blockIdx.y;
  int y = bx >> 1;
  int c0 = ((bx & 1) << 6) + ((wid & 1) << 5);
  int coW = (wid >> 1) << 5;
  size_t ibase = (size_t)b * HWp;

  float4v acc[2][2];
  #pragma unroll
  for (int i = 0; i < 2; i++)
    #pragma unroll
    for (int j = 0; j < 2; j++) acc[i][j] = (float4v){0.f, 0.f, 0.f, 0.f};
  short8 zz = {0, 0, 0, 0, 0, 0, 0, 0};

  #pragma unroll
  for (int k = 0; k < TAPS; k++) {
    int dy = (TAPS == 9) ? (k / 3 - 1) : 0;
    int dx = (TAPS == 9) ? (k % 3 - 1) : 0;
    int yy = y + dy;
    if (TAPS == 9 && (yy < 0 || yy >= Hp)) continue;
    #pragma unroll
    for (int ch = 0; ch < 2; ch++) {
      int ci0 = ch * 32 + q * 8;
      short8 bfr[2], afr[2];
      #pragma unroll
      for (int j = 0; j < 2; j++)
        bfr[j] = *(const short8*)&wt[(size_t)(k * 64 + coW + j * 16 + m) * 64 + ci0];
      #pragma unroll
      for (int i = 0; i < 2; i++) {
        int col = c0 + i * 16 + m + dx;
        bool vld = (TAPS == 1) || ((unsigned)col < (unsigned)Wp);
        int colc = min(max(col, 0), Wp - 1);
        short8 h = *(const short8*)&in[(ibase + (size_t)yy * Wp + colc) * 64 + ci0];
        afr[i] = vld ? h : zz;
      }
      #pragma unroll
      for (int i = 0; i < 2; i++)
        #pragma unroll
        for (int j = 0; j < 2; j++)
          acc[i][j] = __builtin_amdgcn_mfma_f32_16x16x32_bf16(afr[i], bfr[j], acc[i][j], 0, 0, 0);
    }
  }

  #pragma unroll
  for (int j = 0; j < 2; j++) {
    int co = coW + j * 16 + m;
    float bv = bias[co];
    #pragma unroll
    for (int i = 0; i < 2; i++) {
      #pragma unroll
      for (int r = 0; r < 4; r++) {
        size_t px = ibase + (size_t)y * Wp + c0 + i * 16 + q * 4 + r;
        float v = acc[i][j][r] + bv;
        v = v > 0.f ? v : 0.1f * v;
        out[px * 64 + co] = f2b(v);
      }
    }
  }
}

// ---------------- 3x3 pad1 NHWC 64ch conv, 2 rows/block (offset CNN) ----------------
__global__ __launch_bounds__(256)
void conv_bf9r2(const ushortt* __restrict__ in, const ushortt* __restrict__ wt,
                const float* __restrict__ bias, ushortt* __restrict__ out) {
  int tid = threadIdx.x;
  int wid = tid >> 6, lane = tid & 63;
  int q = lane >> 4, m = lane & 15;
  int bx = blockIdx.x, b = blockIdx.y;     // bx in [0,128)
  int y0 = (bx >> 1) * 2;
  int c0 = ((bx & 1) << 6) + ((wid & 1) << 5);
  int coW = (wid >> 1) << 5;
  size_t ibase = (size_t)b * HWp;

  float4v acc[2][2][2];                    // [row][i][j]
  #pragma unroll
  for (int r = 0; r < 2; r++)
    #pragma unroll
    for (int i = 0; i < 2; i++)
      #pragma unroll
      for (int j = 0; j < 2; j++) acc[r][i][j] = (float4v){0.f, 0.f, 0.f, 0.f};
  short8 zz = {0, 0, 0, 0, 0, 0, 0, 0};

  #pragma unroll
  for (int k = 0; k < 9; k++) {
    int dy = k / 3 - 1, dx = k % 3 - 1;
    #pragma unroll
    for (int ch = 0; ch < 2; ch++) {
      int ci0 = ch * 32 + q * 8;
      short8 bfr[2];
      #pragma unroll
      for (int j = 0; j < 2; j++)
        bfr[j] = *(const short8*)&wt[(size_t)(k * 64 + coW + j * 16 + m) * 64 + ci0];
      short8 afr[2][2];
      #pragma unroll
      for (int r = 0; r < 2; r++) {
        int yy = y0 + r + dy;
        bool vy = (yy >= 0 && yy < Hp);
        int yyc = min(max(yy, 0), Hp - 1);
        #pragma unroll
        for (int i = 0; i < 2; i++) {
          int col = c0 + i * 16 + m + dx;
          bool vld = vy && ((unsigned)col < (unsigned)Wp);
          int colc = min(max(col, 0), Wp - 1);
          short8 h = *(const short8*)&in[(ibase + (size_t)yyc * Wp + colc) * 64 + ci0];
          afr[r][i] = vld ? h : zz;
        }
      }
      #pragma unroll
      for (int r = 0; r < 2; r++)
        #pragma unroll
        for (int i = 0; i < 2; i++)
          #pragma unroll
          for (int j = 0; j < 2; j++)
            acc[r][i][j] = __builtin_amdgcn_mfma_f32_16x16x32_bf16(afr[r][i], bfr[j], acc[r][i][j], 0, 0, 0);
    }
  }

  #pragma unroll
  for (int j = 0; j < 2; j++) {
    int co = coW + j * 16 + m;
    float bv = bias[co];
    #pragma unroll
    for (int r = 0; r < 2; r++) {
      #pragma unroll
      for (int i = 0; i < 2; i++) {
        #pragma unroll
        for (int rr = 0; rr < 4; rr++) {
          size_t px = ibase + (size_t)(y0 + r) * Wp + c0 + i * 16 + q * 4 + rr;
          float v = acc[r][i][j][rr] + bv;
          v = v > 0.f ? v : 0.1f * v;
          out[px * 64 + co] = f2b(v);
        }
      }
    }
  }
}

// ---------------- NCHW bf16 -> NHWC bf16 transpose (full batch) ----------------
__global__ __launch_bounds__(256)
void t64b(const ushortt* __restrict__ in, ushortt* __restrict__ out) {
  __shared__ ushortt tl[64 * 65];
  int tid = threadIdx.x;
  int b = blockIdx.y;
  int px0 = blockIdx.x * 64;
  int lpx = tid & 63, c4 = tid >> 6;
  const ushortt* ip = in + (size_t)b * 64 * HWp;
  #pragma unroll
  for (int i = 0; i < 16; i++) {
    int c = c4 + 4 * i;
    tl[lpx * 65 + c] = ip[(size_t)c * HWp + px0 + lpx];
  }
  __syncthreads();
  int ci = tid & 63, pr = tid >> 6;
  #pragma unroll
  for (int i = 0; i < 16; i++) {
    int r = pr + 4 * i;
    out[((size_t)b * HWp + px0 + r) * 64 + ci] = tl[r * 65 + ci];
  }
}

// ---------------- merged weight repack (all segments, 5245 blocks) ----------------
__global__ __launch_bounds__(256)
void repack_all(const float* __restrict__ w1a, const float* __restrict__ w3a,
                const float* __restrict__ w5a, const float* __restrict__ inv2,
                const float* __restrict__ d2, const float* __restrict__ d4,
                const float* __restrict__ d6, const float* __restrict__ ow1,
                const float* __restrict__ ow2, const float* __restrict__ ow3,
                const float* __restrict__ ow4, const float* __restrict__ ow5,
                const float* __restrict__ p1, const float* __restrict__ p2,
                const float* __restrict__ p3, const float* __restrict__ p4,
                ushortt* __restrict__ wb, ushortt* __restrict__ wbi2,
                ushortt* __restrict__ wdwb, ushortt* __restrict__ wc1,
                ushortt* __restrict__ wc2, ushortt* __restrict__ wpw) {
  int b = blockIdx.x;
  int tid = threadIdx.x;
  if (b < 4320) {                       // wie_w1/3/5 -> wb (640-padded, perm)
    int which = b / 1440;
    int idx = (b - which * 1440) * 256 + tid;
    const float* in = which == 0 ? w1a : which == 1 ? w3a : w5a;
    int cop = idx / 576, cip = idx % 576;
    ushortt v = 0;
    if (cop < 576) {
      int co = (cop & 63) * 9 + (cop >> 6);
      int ci = (cip & 63) * 9 + (cip >> 6);
      v = f2b(in[(size_t)co * 576 + ci]);
    }
    wb[(size_t)which * 640 * 576 + idx] = v;
  } else if (b < 4464) {                // inv_w2 -> wbi2
    int idx = (b - 4320) * 256 + tid;
    if (idx < 64 * 576) {
      int co = idx / 576, cip = idx % 576;
      int ci = (cip & 63) * 9 + (cip >> 6);
      wbi2[idx] = f2b(inv2[(size_t)co * 576 + ci]);
    }
  } else if (b < 4525) {                // wie_w2/4/6 dw -> wdwb
    int idx = (b - 4464) * 256 + tid;
    if (idx < 3 * 5184) {
      int which = idx / 5184, r = idx % 5184;
      const float* in = which == 0 ? d2 : which == 1 ? d4 : d6;
      int tap = r / 576, chp = r % 576;
      int ch = (chp & 63) * 9 + (chp >> 6);
      wdwb[idx] = f2b(in[ch * 9 + tap]);
    }
  } else if (b < 4541) {                // off_w1 -> wc1
    int idx = (b - 4525) * 256 + tid;
    if (idx < 4096) wc1[idx] = f2b(ow1[idx]);
  } else if (b < 5117) {                // off_w2..5 -> wc2
    int bb = b - 4541;
    int which = bb / 144;
    int idx = (bb - which * 144) * 256 + tid;
    if (idx < 36864) {
      const float* in = which == 0 ? ow2 : which == 1 ? ow3 : which == 2 ? ow4 : ow5;
      int k = idx >> 12, r = idx & 4095;
      int co = r >> 6, ci = r & 63;
      wc2[which * 36864 + idx] = f2b(in[(size_t)(co * 64 + ci) * 9 + k]);
    }
  } else {                              // enc/dec pw -> wpw
    int bb = b - 5117;
    int which = bb / 32;
    int idx = (bb - which * 32) * 256 + tid;
    if (idx < 8192) {
      const float* in = which == 0 ? p1 : which == 1 ? p2 : which == 2 ? p3 : p4;
      wpw[which * 8192 + idx] = f2b(in[idx]);
    }
  }
}

// ---------------- off_w6 -> NCHW offsets, 8*tanh ----------------
__global__ __launch_bounds__(256)
void off6_nhwc(const ushortt* __restrict__ hi, const float* __restrict__ wgt,
               const float* __restrict__ bias, float* __restrict__ out) {
  __shared__ float Wl[18 * 64];
  for (int i = threadIdx.x; i < 18 * 64; i += 256) Wl[i] = wgt[i];
  __syncthreads();
  int px = blockIdx.x * 256 + threadIdx.x;
  int b = px >> 14, pim = px & 16383;
  float acc[18];
  #pragma unroll
  for (int j = 0; j < 18; j++) acc[j] = 0.f;
  const uint4* ph = (const uint4*)(hi + (size_t)px * 64);
  for (int g = 0; g < 8; g++) {
    uint4 H = ph[g];
    u32 hw[4] = {H.x, H.y, H.z, H.w};
    #pragma unroll
    for (int t = 0; t < 4; t++) {
      float v0 = blo(hw[t]);
      float v1 = bhi(hw[t]);
      int ci = g * 8 + t * 2;
      #pragma unroll
      for (int j = 0; j < 18; j++)
        acc[j] += Wl[j * 64 + ci] * v0 + Wl[j * 64 + ci + 1] * v1;
    }
  }
  #pragma unroll
  for (int j = 0; j < 18; j++)
    out[((size_t)b * 18 + j) * HWp + pim] = 8.f * tanhf(acc[j] + bias[j]);
}

// ---------------- deform v2: 4ch/lane uint2 gathers, 4px/wave, XCD row-aligned ----------------
__global__ __launch_bounds__(256)
void deform_x(const ushortt* __restrict__ xn0, const float* __restrict__ offs0,
              ushortt* __restrict__ xb) {
  int lin = blockIdx.x;
  int xcd = lin & 7, local = lin >> 3;    // [0,256)
  int rowi = local >> 3, bx = local & 7;
  int tid = threadIdx.x;
  int wid = tid >> 6, lane = tid & 63;
  int c4 = lane & 15, ps = lane >> 4;     // 16 lanes/px, 4 ch/lane; 4 px/wave
  int pg = (xcd * 32 + rowi) * 128 + bx * 16 + wid * 4 + ps;
  int bl = pg >> 14, p = pg & 16383;
  const ushortt* xn = xn0 + (size_t)bl * HWp * 64;
  const float* offs = offs0 + (size_t)bl * 18 * HWp;
  int yi = p >> 7, xi = p & 127;
  #pragma unroll
  for (int k = 0; k < 9; k++) {
    float dy = offs[(size_t)(2 * k) * HWp + p];
    float dx = offs[(size_t)(2 * k + 1) * HWp + p];
    float py = (float)yi + (float)(k / 3 - 1) + dy;
    float px = (float)xi + (float)(k % 3 - 1) + dx;
    float y0f = floorf(py), x0f = floorf(px);
    float wy1 = py - y0f, wy0 = 1.f - wy1;
    float wx1 = px - x0f, wx0 = 1.f - wx1;
    int y0 = (int)y0f, x0 = (int)x0f;
    bool vy0 = (y0 >= 0 && y0 < Hp), vy1 = (y0 + 1 >= 0 && y0 + 1 < Hp);
    bool vx0 = (x0 >= 0 && x0 < Wp), vx1 = (x0 + 1 >= 0 && x0 + 1 < Wp);
    int yc0 = min(max(y0, 0), Hp - 1), yc1 = min(max(y0 + 1, 0), Hp - 1);
    int xc0 = min(max(x0, 0), Wp - 1), xc1 = min(max(x0 + 1, 0), Wp - 1);
    float w00 = wy0 * wx0 * ((vy0 && vx0) ? 1.f : 0.f);
    float w01 = wy0 * wx1 * ((vy0 && vx1) ? 1.f : 0.f);
    float w10 = wy1 * wx0 * ((vy1 && vx0) ? 1.f : 0.f);
    float w11 = wy1 * wx1 * ((vy1 && vx1) ? 1.f : 0.f);
    uint2 t00 = *(const uint2*)&xn[(size_t)(yc0 * Wp + xc0) * 64 + c4 * 4];
    uint2 t01 = *(const uint2*)&xn[(size_t)(yc0 * Wp + xc1) * 64 + c4 * 4];
    uint2 t10 = *(const uint2*)&xn[(size_t)(yc1 * Wp + xc0) * 64 + c4 * 4];
    uint2 t11 = *(const uint2*)&xn[(size_t)(yc1 * Wp + xc1) * 64 + c4 * 4];
    float a0 = blo(t00.x) * w00 + blo(t01.x) * w01 + blo(t10.x) * w10 + blo(t11.x) * w11;
    float b0 = bhi(t00.x) * w00 + bhi(t01.x) * w01 + bhi(t10.x) * w10 + bhi(t11.x) * w11;
    float a1 = blo(t00.y) * w00 + blo(t01.y) * w01 + blo(t10.y) * w10 + blo(t11.y) * w11;
    float b1 = bhi(t00.y) * w00 + bhi(t01.y) * w01 + bhi(t10.y) * w10 + bhi(t11.y) * w11;
    uint2 st;
    st.x = (u32)f2b(a0) | (((u32)f2b(b0)) << 16);
    st.y = (u32)f2b(a1) | (((u32)f2b(b1)) << 16);
    *(uint2*)&xb[(size_t)pg * 576 + 64 * k + c4 * 4] = st;
  }
}

// ---------------- MFMA bf16 GEMM, 128x128 tile, XCD-partitioned ----------------
// v2 (measured best): 2-phase double-buffered LDS + swapped-operand coalesced
// epilogue. v3/v4/v5 all regressed -> this is the structure's floor.
__global__ __launch_bounds__(256)
void gemm128(const ushortt* __restrict__ X, const ushortt* __restrict__ Wb,
             ushortt* __restrict__ out) {
  __shared__ ushortt Xs[2][4096];
  __shared__ ushortt Wsh[2][4096];
  int tid = threadIdx.x;
  int lin = blockIdx.x + blockIdx.y * 5;
  int xcd = lin & 7, loc = lin >> 3;
  int co_t = loc % 5;
  int px_t = xcd * 32 + loc / 5;
  int co0 = co_t * 128, px0 = px_t * 128;
  int r0 = tid >> 2;
  int sch = (tid & 3) ^ ((tid >> 3) & 3);
  size_t gx0 = (size_t)(px0 + r0) * 576 + sch * 8;
  size_t gx1 = gx0 + (size_t)64 * 576;
  size_t gw0 = (size_t)(co0 + r0) * 576 + sch * 8;
  size_t gw1 = gw0 + (size_t)64 * 576;
  int wid = tid >> 6, lane = tid & 63;
  int q = lane >> 4, m = lane & 15;
  int qx = (q ^ ((m >> 1) & 3)) * 8;
  int pxh = (wid & 1) * 64, coh = (wid >> 1) * 64;
  float4v acc[4][4];
  #pragma unroll
  for (int i = 0; i < 4; i++)
    #pragma unroll
    for (int j = 0; j < 4; j++) acc[i][j] = (float4v){0.f, 0.f, 0.f, 0.f};

  // prologue: stage K-step 0 into buffer 0
  gll(X + gx0,  &Xs[0][tid * 8]);
  gll(X + gx1,  &Xs[0][2048 + tid * 8]);
  gll(Wb + gw0, &Wsh[0][tid * 8]);
  gll(Wb + gw1, &Wsh[0][2048 + tid * 8]);
  __syncthreads();

  int cur = 0;
  for (int k0 = 0; k0 < 576; k0 += 32) {
    if (k0 + 32 < 576) {               // prefetch next K-step into other buffer
      gll(X + gx0 + k0 + 32,  &Xs[cur ^ 1][tid * 8]);
      gll(X + gx1 + k0 + 32,  &Xs[cur ^ 1][2048 + tid * 8]);
      gll(Wb + gw0 + k0 + 32, &Wsh[cur ^ 1][tid * 8]);
      gll(Wb + gw1 + k0 + 32, &Wsh[cur ^ 1][2048 + tid * 8]);
    }
    short8 a[4], b[4];
    #pragma unroll
    for (int i = 0; i < 4; i++)
      a[i] = *(const short8*)&Xs[cur][(pxh + i * 16 + m) * 32 + qx];
    #pragma unroll
    for (int j = 0; j < 4; j++)
      b[j] = *(const short8*)&Wsh[cur][(coh + j * 16 + m) * 32 + qx];
    #pragma unroll
    for (int i = 0; i < 4; i++)
      #pragma unroll
      for (int j = 0; j < 4; j++)
        acc[i][j] = __builtin_amdgcn_mfma_f32_16x16x32_bf16(b[j], a[i], acc[i][j], 0, 0, 0);
    __syncthreads();                   // drains prefetch (vmcnt0) + LDS reads
    cur ^= 1;
  }

  // epilogue: swapped orientation -> reg index r runs along co (contiguous)
  #pragma unroll
  for (int j = 0; j < 4; j++) {
    int cob = co0 + coh + j * 16 + q * 4;
    if (cob >= 576) continue;
    #pragma unroll
    for (int i = 0; i < 4; i++) {
      size_t px = (size_t)(px0 + pxh + i * 16 + m);
      u32 lo = (u32)f2b(acc[i][j][0]) | (((u32)f2b(acc[i][j][1])) << 16);
      u32 hi = (u32)f2b(acc[i][j][2]) | (((u32)f2b(acc[i][j][3])) << 16);
      uint2 st; st.x = lo; st.y = hi;
      *(uint2*)&out[px * 576 + cob] = st;
    }
  }
}

// ---------------- MFMA bf16 GEMM 576->64 (inv2), out fp32 NCHW, XCD row-aligned ----------------
// v2: 2-phase double-buffered K-loop (verified transformation).
__global__ __launch_bounds__(256)
void gemm64o2(const ushortt* __restrict__ X, const ushortt* __restrict__ Wb,
              float* __restrict__ outv) {
  __shared__ ushortt Xs[2][4096];
  __shared__ ushortt Wsh[2][2048];
  int tid = threadIdx.x;
  int lin = blockIdx.x;
  int xcd = lin & 7, local = lin >> 3;      // [0,32)
  int px0 = (xcd * 32 + local) * 128;
  int srow = tid >> 2;
  int sch = (tid & 3) ^ ((tid >> 3) & 3);
  size_t gxo0 = (size_t)(px0 + srow) * 576 + sch * 8;
  size_t gxo1 = gxo0 + (size_t)64 * 576;
  size_t gwo  = (size_t)srow * 576 + sch * 8;
  int wid = tid >> 6, lane = tid & 63;
  int q = lane >> 4, m = lane & 15;
  int qx = (q ^ ((m >> 1) & 3)) * 8;
  int pxh = (wid & 1) * 64, coh = (wid >> 1) * 32;
  float4v acc[4][2];
  #pragma unroll
  for (int i = 0; i < 4; i++)
    #pragma unroll
    for (int j = 0; j < 2; j++) acc[i][j] = (float4v){0.f, 0.f, 0.f, 0.f};

  // prologue: stage K-step 0 into buffer 0
  gll(X + gxo0,  &Xs[0][tid * 8]);
  gll(X + gxo1,  &Xs[0][2048 + tid * 8]);
  gll(Wb + gwo,  &Wsh[0][tid * 8]);
  __syncthreads();

  int cur = 0;
  for (int k0 = 0; k0 < 576; k0 += 32) {
    if (k0 + 32 < 576) {               // prefetch next K-step into other buffer
      gll(X + gxo0 + k0 + 32,  &Xs[cur ^ 1][tid * 8]);
      gll(X + gxo1 + k0 + 32,  &Xs[cur ^ 1][2048 + tid * 8]);
      gll(Wb + gwo + k0 + 32,  &Wsh[cur ^ 1][tid * 8]);
    }
    short8 a[4], b[2];
    #pragma unroll
    for (int i = 0; i < 4; i++)
      a[i] = *(const short8*)&Xs[cur][(pxh + i * 16 + m) * 32 + qx];
    #pragma unroll
    for (int j = 0; j < 2; j++)
      b[j] = *(const short8*)&Wsh[cur][(coh + j * 16 + m) * 32 + qx];
    #pragma unroll
    for (int i = 0; i < 4; i++)
      #pragma unroll
      for (int j = 0; j < 2; j++)
        acc[i][j] = __builtin_amdgcn_mfma_f32_16x16x32_bf16(a[i], b[j], acc[i][j], 0, 0, 0);
    __syncthreads();                   // drains prefetch + LDS reads
    cur ^= 1;
  }

  #pragma unroll
  for (int j = 0; j < 2; j++) {
    int co = coh + j * 16 + m;
    #pragma unroll
    for (int i = 0; i < 4; i++) {
      int pxb = px0 + pxh + i * 16 + q * 4;
      int bl = pxb >> 14, pim = pxb & 16383;
      float4 r;
      r.x = acc[i][j][0]; r.y = acc[i][j][1];
      r.z = acc[i][j][2]; r.w = acc[i][j][3];
      *(float4*)&outv[(size_t)(bl * 64 + co) * HWp + pim] = r;
    }
  }
}

// ---------------- depthwise 3x3 NHWC bf16 v3: XCD row-aligned, 8ch x 4 rows ----------------
template<int ACT>
__global__ __launch_bounds__(256)
void dw3x3_v3(const ushortt* __restrict__ in, const ushortt* __restrict__ wt,
              ushortt* __restrict__ out) {
  int lin = blockIdx.x;
  int xcd = lin & 7, local = lin >> 3;     // [0,344)
  int g = local / 43, bxq = local - g * 43;
  int rg = xcd * 8 + g;                    // combined row-group [0,64)
  int bz = rg >> 5, by = rg & 31;
  int tid = threadIdx.x;
  int pxl = tid / 72;
  int gg = tid - pxl * 72;
  if (pxl >= 3) return;
  int x = bxq * 3 + pxl;
  if (x >= Wp) return;
  int y0 = by * 4;
  size_t bbase = (size_t)bz * HWp;

  float w[9][8];
  #pragma unroll
  for (int t = 0; t < 9; t++) {
    uint4 wv = *(const uint4*)&wt[t * 576 + gg * 8];
    u32 wsw[4] = {wv.x, wv.y, wv.z, wv.w};
    #pragma unroll
    for (int p = 0; p < 4; p++) {
      w[t][2 * p]     = blo(wsw[p]);
      w[t][2 * p + 1] = bhi(wsw[p]);
    }
  }
  float acc[4][8];
  #pragma unroll
  for (int o = 0; o < 4; o++)
    #pragma unroll
    for (int c = 0; c < 8; c++) acc[o][c] = 0.f;

  #pragma unroll
  for (int ri = 0; ri < 6; ri++) {
    int yy = y0 - 1 + ri;
    bool vr = (yy >= 0 && yy < Hp);
    float v[3][8];
    #pragma unroll
    for (int dx = 0; dx < 3; dx++) {
      int xx = x + dx - 1;
      uint4 t4 = {0, 0, 0, 0};
      if (vr && xx >= 0 && xx < Wp)
        t4 = *(const uint4*)&in[(bbase + (size_t)yy * Wp + xx) * 576 + gg * 8];
      u32 tw[4] = {t4.x, t4.y, t4.z, t4.w};
      #pragma unroll
      for (int p = 0; p < 4; p++) {
        v[dx][2 * p]     = blo(tw[p]);
        v[dx][2 * p + 1] = bhi(tw[p]);
      }
    }
    #pragma unroll
    for (int o = 0; o < 4; o++) {
      int dy = ri - o;
      if (dy < 0 || dy > 2) continue;
      #pragma unroll
      for (int dx = 0; dx < 3; dx++)
        #pragma unroll
        for (int c = 0; c < 8; c++)
          acc[o][c] += w[dy * 3 + dx][c] * v[dx][c];
    }
  }

  #pragma unroll
  for (int o = 0; o < 4; o++) {
    int yy = y0 + o;
    u32 pk[4];
    #pragma unroll
    for (int p = 0; p < 4; p++) {
      float r0 = acc[o][2 * p], r1 = acc[o][2 * p + 1];
      if (ACT == 1) { r0 = fmaxf(r0, 0.f); r1 = fmaxf(r1, 0.f); }
      else { r0 = 1.f / (1.f + __expf(-r0)); r1 = 1.f / (1.f + __expf(-r1)); }
      pk[p] = (u32)f2b(r0) | (((u32)f2b(r1)) << 16);
    }
    uint4 o4; o4.x = pk[0]; o4.y = pk[1]; o4.z = pk[2]; o4.w = pk[3];
    *(uint4*)&out[(bbase + (size_t)yy * Wp + x) * 576 + gg * 8] = o4;
  }
}

// ---------------- g9inv2 v2 (best measured): 4 px/thread, 16 px/block, grid 2048 ----------------
__global__ __launch_bounds__(256)
void g9inv2(const ushortt* __restrict__ wien, const ushortt* __restrict__ xb,
            const float* __restrict__ wdct, const float* __restrict__ winv,
            ushortt* __restrict__ outb) {
  __shared__ float Wd[5184];
  __shared__ float Wi[5184];
  for (int i = threadIdx.x; i < 5184; i += 256) {
    Wd[i] = wdct[i];
    Wi[i] = winv[i];
  }
  __syncthreads();
  int lin = blockIdx.x;
  int xcd = lin & 7, local = lin >> 3;     // [0,256)
  int rowi = local >> 3, bx = local & 7;
  int pslot = threadIdx.x >> 6;
  int c = threadIdx.x & 63;
  size_t px0 = (size_t)((xcd * 32 + rowi) * 128 + bx * 16 + pslot * 4);
  const float* wd = &Wd[c * 81];
  const float* wi = &Wi[c * 81];

  float xr[4][9];
  #pragma unroll
  for (int u = 0; u < 4; u++)
    #pragma unroll
    for (int t = 0; t < 9; t++)
      xr[u][t] = b2f(xb[(px0 + u) * 576 + 64 * t + c]);

  float wv[4][9];
  #pragma unroll
  for (int u = 0; u < 4; u++)
    #pragma unroll
    for (int o = 0; o < 9; o++)
      wv[u][o] = b2f(wien[(px0 + u) * 576 + 64 * o + c]);

  float v[4][9];
  #pragma unroll
  for (int o = 0; o < 9; o++) {
    #pragma unroll
    for (int u = 0; u < 4; u++) {
      float d = 0.f;
      #pragma unroll
      for (int t = 0; t < 9; t++) d += wd[o * 9 + t] * xr[u][t];
      v[u][o] = wv[u][o] * d;
    }
  }
  #pragma unroll
  for (int j = 0; j < 9; j++) {
    #pragma unroll
    for (int u = 0; u < 4; u++) {
      float a = 0.f;
      #pragma unroll
      for (int o = 0; o < 9; o++) a += wi[j * 9 + o] * v[u][o];
      outb[(px0 + u) * 576 + 64 * j + c] = f2b(a);
    }
  }
}

// ---------------- launch ----------------
extern "C" void kernel_launch(void* const* d_in, const int* in_sizes, int n_in,
                              void* d_out, int out_size, void* d_ws, size_t ws_size,
                              hipStream_t stream) {
  const float* x       = (const float*)d_in[0];
  const float* enc_dw  = (const float*)d_in[1];
  const float* enc_pw1 = (const float*)d_in[2];
  const float* enc_pw2 = (const float*)d_in[3];
  const float* dec_dw  = (const float*)d_in[4];
  const float* dec_pw1 = (const float*)d_in[5];
  const float* dec_pw2 = (const float*)d_in[6];
  const float* off_w1  = (const float*)d_in[7];
  const float* off_b1  = (const float*)d_in[8];
  const float* off_w2  = (const float*)d_in[9];
  const float* off_b2  = (const float*)d_in[10];
  const float* off_w3  = (const float*)d_in[11];
  const float* off_b3  = (const float*)d_in[12];
  const float* off_w4  = (const float*)d_in[13];
  const float* off_b4  = (const float*)d_in[14];
  const float* off_w5  = (const float*)d_in[15];
  const float* off_b5  = (const float*)d_in[16];
  const float* off_w6  = (const float*)d_in[17];
  const float* off_b6  = (const float*)d_in[18];
  const float* dct_w   = (const float*)d_in[19];
  const float* wie_w1  = (const float*)d_in[20];
  const float* wie_w2  = (const float*)d_in[21];
  const float* wie_w3  = (const float*)d_in[22];
  const float* wie_w4  = (const float*)d_in[23];
  const float* wie_w5  = (const float*)d_in[24];
  const float* wie_w6  = (const float*)d_in[25];
  const float* inv_w1  = (const float*)d_in[26];
  const float* inv_w2  = (const float*)d_in[27];
  float* outp = (float*)d_out;

  const size_t NP = (size_t)Bp * HWp;
  const size_t REQ_FLOATS = NP * 64 + NP * 64 + NP * 128 +
                            2 * (size_t)HWp * CKp + (size_t)HWp * CKp;
  if (ws_size < REQ_FLOATS * sizeof(float)) return;

  float* ws  = (float*)d_ws;
  float* x1  = ws;
  float* t0  = x1 + NP * 64;
  float* t1  = t0 + NP * 64;
  float* bigA = t1 + NP * 128;
  float* bigB = bigA + (size_t)HWp * CKp;
  float* bigC = bigB + (size_t)HWp * CKp;
  ushortt* R1 = (ushortt*)bigA;
  ushortt* R2 = (ushortt*)bigB;
  ushortt* R3 = (ushortt*)bigC;
  ushortt* e1 = (ushortt*)bigA;

  float* wreg = t0 + NP * 18;
  ushortt* wb  = (ushortt*)wreg;
  ushortt* wbi2 = wb + 3 * 640 * 576;
  ushortt* wdwb = wbi2 + 64 * 576;
  ushortt* wc1  = wdwb + 3 * 5184;
  ushortt* wc2  = wc1 + 4096;
  ushortt* wpw  = wc2 + 4 * 36864;

  ushortt* xnAll = (ushortt*)t1;
  ushortt* oA = xnAll + NP * 64;
  ushortt* oB = oA + NP * 64;

  float* offs = t0;
  float* mid  = x1;

  dim3 blk(256);

  // ---- enc ConvNeXt: dw7 fp32->bf16, pw via bf16 MFMA ----
  dwconv7_lds<<<dim3(Hp / 2, Bp * Cp), blk, 0, stream>>>(x, enc_dw, (ushortt*)t0);
  t64b<<<dim3(HWp / 64, Bp), blk, 0, stream>>>((const ushortt*)t0, oA);

  // ---- merged weight repack ----
  repack_all<<<dim3(5245), blk, 0, stream>>>(
      wie_w1, wie_w3, wie_w5, inv_w2, wie_w2, wie_w4, wie_w6, off_w1,
      off_w2, off_w3, off_w4, off_w5, enc_pw1, enc_pw2, dec_pw1, dec_pw2,
      wb, wbi2, wdwb, wc1, wc2, wpw);

  pw_bf<64, 1, 0><<<dim3(NP / 128, 2), blk, 0, stream>>>(oA, wpw, nullptr, e1, 128);
  pw_bf<128, 0, 1><<<dim3(NP / 128, 1), blk, 0, stream>>>(e1, wpw + 8192, x, xnAll, 64);

  // ---- offset CNN (full batch, bf16 MFMA, NHWC; 3x3 layers 2-row) ----
  conv_bf<1><<<dim3(HWp / 64, Bp), blk, 0, stream>>>(xnAll, wc1, off_b1, oA);
  conv_bf9r2<<<dim3(128, Bp), blk, 0, stream>>>(oA, wc2,             off_b2, oB);
  conv_bf9r2<<<dim3(128, Bp), blk, 0, stream>>>(oB, wc2 + 36864,     off_b3, oA);
  conv_bf9r2<<<dim3(128, Bp), blk, 0, stream>>>(oA, wc2 + 2 * 36864, off_b4, oB);
  conv_bf9r2<<<dim3(128, Bp), blk, 0, stream>>>(oB, wc2 + 3 * 36864, off_b5, oA);
  off6_nhwc<<<dim3(NP / 256), blk, 0, stream>>>(oA, off_w6, off_b6, offs);

  // ---- 576-channel middle: 2 batches per pass; xb persists in R2 ----
  for (int bp = 0; bp < 2; bp++) {
    const ushortt* xn0 = xnAll + (size_t)(2 * bp) * HWp * 64;
    const float* off0 = offs + (size_t)(2 * bp) * 18 * HWp;
    float* mid0 = mid + (size_t)(2 * bp) * 64 * HWp;

    deform_x<<<dim3(2048), blk, 0, stream>>>(xn0, off0, R2);
    gemm128<<<dim3(5, 256), blk, 0, stream>>>(R2, wb, R3);
    dw3x3_v3<1><<<dim3(2752), blk, 0, stream>>>(R3, wdwb, R1);
    gemm128<<<dim3(5, 256), blk, 0, stream>>>(R1, wb + 640 * 576, R3);
    dw3x3_v3<1><<<dim3(2752), blk, 0, stream>>>(R3, wdwb + 5184, R1);
    gemm128<<<dim3(5, 256), blk, 0, stream>>>(R1, wb + 2 * 640 * 576, R3);
    dw3x3_v3<2><<<dim3(2752), blk, 0, stream>>>(R3, wdwb + 2 * 5184, R1);  // wiener
    g9inv2<<<dim3(2048), blk, 0, stream>>>(R1, R2, dct_w, inv_w1, R3);
    gemm64o2<<<dim3(256), blk, 0, stream>>>(R3, wbi2, mid0);
  }

  // ---- dec ConvNeXt: dw7 fp32->bf16 (tmp in bigB), pw via bf16 MFMA ----
  dwconv7_lds<<<dim3(Hp / 2, Bp * Cp), blk, 0, stream>>>(mid, dec_dw, (ushortt*)bigB);
  t64b<<<dim3(HWp / 64, Bp), blk, 0, stream>>>((const ushortt*)bigB, oA);
  pw_bf<64, 1, 0><<<dim3(NP / 128, 2), blk, 0, stream>>>(oA, wpw + 2 * 8192, nullptr, e1, 128);
  pw_bf<128, 0, 2><<<dim3(NP / 128, 1), blk, 0, stream>>>(e1, wpw + 3 * 8192, mid, outp, 64);
}

// Round 21
// 822.606 us; speedup vs baseline: 1.0341x; 1.0163x over previous
//
#include <hip/hip_runtime.h>
#include <math.h>

#define HWp 16384
#define Wp 128
#define Hp 128
#define Bp 4
#define Cp 64
#define CKp 576

typedef unsigned int u32;
typedef unsigned short ushortt;
typedef __attribute__((ext_vector_type(8))) short short8;
typedef __attribute__((ext_vector_type(4))) float float4v;

__device__ __forceinline__ ushortt f2b(float f) {
  union { float f; u32 u; } x; x.f = f;
  u32 r = x.u + 0x7fff + ((x.u >> 16) & 1);
  return (ushortt)(r >> 16);
}
__device__ __forceinline__ float b2f(ushortt h) {
  union { u32 u; float f; } x; x.u = ((u32)h) << 16; return x.f;
}
__device__ __forceinline__ float blo(u32 t) {
  union { u32 u; float f; } x; x.u = t << 16; return x.f;
}
__device__ __forceinline__ float bhi(u32 t) {
  union { u32 u; float f; } x; x.u = t & 0xffff0000u; return x.f;
}
__device__ __forceinline__ void gll(const ushortt* g, ushortt* l) {
  __builtin_amdgcn_global_load_lds(
      (const __attribute__((address_space(1))) u32*)g,
      (__attribute__((address_space(3))) u32*)l, 16, 0, 0);
}

// ---------------- depthwise 7x7, pad 3, LDS-tiled (NCHW in, bf16 NCHW out) ----------------
__global__ __launch_bounds__(256)
void dwconv7_lds(const float* __restrict__ in, const float* __restrict__ w,
                 ushortt* __restrict__ out) {
  int bc = blockIdx.y;
  int tid = threadIdx.x;
  int y0 = blockIdx.x * 2;
  __shared__ float ws[49];
  __shared__ float tile[8][136];
  if (tid < 49) ws[tid] = w[(bc & 63) * 49 + tid];
  if (tid < 48) {
    int r = tid / 6, cc = tid % 6;
    tile[r][cc < 3 ? cc : 128 + cc] = 0.f;
  }
  const float* ip = in + (size_t)bc * HWp;
  #pragma unroll
  for (int i = 0; i < 4; i++) {
    int idx = tid + 256 * i;
    int r = idx >> 7, xx = idx & 127;
    int yy = y0 - 3 + r;
    tile[r][xx + 3] = (yy >= 0 && yy < Hp) ? ip[yy * Wp + xx] : 0.f;
  }
  __syncthreads();
  int ty = tid >> 7, x = tid & 127;
  float acc = 0.f;
  #pragma unroll
  for (int dy = 0; dy < 7; dy++)
    #pragma unroll
    for (int dx = 0; dx < 7; dx++)
      acc += tile[ty + dy][x + dx] * ws[dy * 7 + dx];
  out[(size_t)bc * HWp + (y0 + ty) * Wp + x] = f2b(acc);
}

// ---------------- bf16 MFMA pointwise conv (enc/dec ConvNeXt pw) ----------------
template<int CIN, int ACT, int MODE>
__global__ __launch_bounds__(256)
void pw_bf(const ushortt* __restrict__ in, const ushortt* __restrict__ wt,
           const float* __restrict__ resid, void* __restrict__ outv, int Cout) {
  int tid = threadIdx.x;
  int wid = tid >> 6, lane = tid & 63;
  int q = lane >> 4, m = lane & 15;
  int px0 = blockIdx.x * 128, co0 = blockIdx.y * 64;
  int pxh = (wid & 1) * 64, coh = (wid >> 1) * 32;
  float4v acc[4][2];
  #pragma unroll
  for (int i = 0; i < 4; i++)
    #pragma unroll
    for (int j = 0; j < 2; j++) acc[i][j] = (float4v){0.f, 0.f, 0.f, 0.f};

  #pragma unroll
  for (int k0 = 0; k0 < CIN; k0 += 32) {
    short8 a[4], b[2];
    #pragma unroll
    for (int j = 0; j < 2; j++)
      b[j] = *(const short8*)&wt[(size_t)(co0 + coh + j * 16 + m) * CIN + k0 + q * 8];
    #pragma unroll
    for (int i = 0; i < 4; i++)
      a[i] = *(const short8*)&in[(size_t)(px0 + pxh + i * 16 + m) * CIN + k0 + q * 8];
    #pragma unroll
    for (int i = 0; i < 4; i++)
      #pragma unroll
      for (int j = 0; j < 2; j++)
        acc[i][j] = __builtin_amdgcn_mfma_f32_16x16x32_bf16(a[i], b[j], acc[i][j], 0, 0, 0);
  }

  #pragma unroll
  for (int j = 0; j < 2; j++) {
    int co = co0 + coh + j * 16 + m;
    #pragma unroll
    for (int i = 0; i < 4; i++) {
      int pxb = px0 + pxh + i * 16 + q * 4;
      int bl = pxb >> 14, pim = pxb & 16383;
      if (MODE == 0) {
        #pragma unroll
        for (int r = 0; r < 4; r++) {
          float v = acc[i][j][r];
          if (ACT == 1) v = fmaxf(v, 0.f);
          ((ushortt*)outv)[(size_t)(pxb + r) * Cout + co] = f2b(v);
        }
      } else {
        float4 rr = *(const float4*)&resid[(size_t)(bl * 64 + co) * HWp + pim];
        float v0 = acc[i][j][0] + rr.x, v1 = acc[i][j][1] + rr.y;
        float v2 = acc[i][j][2] + rr.z, v3 = acc[i][j][3] + rr.w;
        if (MODE == 1) {
          ushortt* ob = (ushortt*)outv;
          ob[(size_t)(pxb + 0) * 64 + co] = f2b(v0);
          ob[(size_t)(pxb + 1) * 64 + co] = f2b(v1);
          ob[(size_t)(pxb + 2) * 64 + co] = f2b(v2);
          ob[(size_t)(pxb + 3) * 64 + co] = f2b(v3);
        } else {
          float4 w4; w4.x = v0; w4.y = v1; w4.z = v2; w4.w = v3;
          *(float4*)&((float*)outv)[(size_t)(bl * 64 + co) * HWp + pim] = w4;
        }
      }
    }
  }
}

// ---------------- plain-bf16 MFMA conv 1x1, NHWC 64ch ----------------
template<int TAPS>
__global__ __launch_bounds__(256)
void conv_bf(const ushortt* __restrict__ in, const ushortt* __restrict__ wt,
             const float* __restrict__ bias, ushortt* __restrict__ out) {
  int tid = threadIdx.x;
  int wid = tid >> 6, lane = tid & 63;
  int q = lane >> 4, m = lane & 15;
  int bx = blockIdx.x, b = blockIdx.y;
  int y = bx >> 1;
  int c0 = ((bx & 1) << 6) + ((wid & 1) << 5);
  int coW = (wid >> 1) << 5;
  size_t ibase = (size_t)b * HWp;

  float4v acc[2][2];
  #pragma unroll
  for (int i = 0; i < 2; i++)
    #pragma unroll
    for (int j = 0; j < 2; j++) acc[i][j] = (float4v){0.f, 0.f, 0.f, 0.f};
  short8 zz = {0, 0, 0, 0, 0, 0, 0, 0};

  #pragma unroll
  for (int k = 0; k < TAPS; k++) {
    int dy = (TAPS == 9) ? (k / 3 - 1) : 0;
    int dx = (TAPS == 9) ? (k % 3 - 1) : 0;
    int yy = y + dy;
    if (TAPS == 9 && (yy < 0 || yy >= Hp)) continue;
    #pragma unroll
    for (int ch = 0; ch < 2; ch++) {
      int ci0 = ch * 32 + q * 8;
      short8 bfr[2], afr[2];
      #pragma unroll
      for (int j = 0; j < 2; j++)
        bfr[j] = *(const short8*)&wt[(size_t)(k * 64 + coW + j * 16 + m) * 64 + ci0];
      #pragma unroll
      for (int i = 0; i < 2; i++) {
        int col = c0 + i * 16 + m + dx;
        bool vld = (TAPS == 1) || ((unsigned)col < (unsigned)Wp);
        int colc = min(max(col, 0), Wp - 1);
        short8 h = *(const short8*)&in[(ibase + (size_t)yy * Wp + colc) * 64 + ci0];
        afr[i] = vld ? h : zz;
      }
      #pragma unroll
      for (int i = 0; i < 2; i++)
        #pragma unroll
        for (int j = 0; j < 2; j++)
          acc[i][j] = __builtin_amdgcn_mfma_f32_16x16x32_bf16(afr[i], bfr[j], acc[i][j], 0, 0, 0);
    }
  }

  #pragma unroll
  for (int j = 0; j < 2; j++) {
    int co = coW + j * 16 + m;
    float bv = bias[co];
    #pragma unroll
    for (int i = 0; i < 2; i++) {
      #pragma unroll
      for (int r = 0; r < 4; r++) {
        size_t px = ibase + (size_t)y * Wp + c0 + i * 16 + q * 4 + r;
        float v = acc[i][j][r] + bv;
        v = v > 0.f ? v : 0.1f * v;
        out[px * 64 + co] = f2b(v);
      }
    }
  }
}

// ---------------- 3x3 pad1 NHWC 64ch conv, 2 rows/block (offset CNN) ----------------
__global__ __launch_bounds__(256)
void conv_bf9r2(const ushortt* __restrict__ in, const ushortt* __restrict__ wt,
                const float* __restrict__ bias, ushortt* __restrict__ out) {
  int tid = threadIdx.x;
  int wid = tid >> 6, lane = tid & 63;
  int q = lane >> 4, m = lane & 15;
  int bx = blockIdx.x, b = blockIdx.y;     // bx in [0,128)
  int y0 = (bx >> 1) * 2;
  int c0 = ((bx & 1) << 6) + ((wid & 1) << 5);
  int coW = (wid >> 1) << 5;
  size_t ibase = (size_t)b * HWp;

  float4v acc[2][2][2];                    // [row][i][j]
  #pragma unroll
  for (int r = 0; r < 2; r++)
    #pragma unroll
    for (int i = 0; i < 2; i++)
      #pragma unroll
      for (int j = 0; j < 2; j++) acc[r][i][j] = (float4v){0.f, 0.f, 0.f, 0.f};
  short8 zz = {0, 0, 0, 0, 0, 0, 0, 0};

  #pragma unroll
  for (int k = 0; k < 9; k++) {
    int dy = k / 3 - 1, dx = k % 3 - 1;
    #pragma unroll
    for (int ch = 0; ch < 2; ch++) {
      int ci0 = ch * 32 + q * 8;
      short8 bfr[2];
      #pragma unroll
      for (int j = 0; j < 2; j++)
        bfr[j] = *(const short8*)&wt[(size_t)(k * 64 + coW + j * 16 + m) * 64 + ci0];
      short8 afr[2][2];
      #pragma unroll
      for (int r = 0; r < 2; r++) {
        int yy = y0 + r + dy;
        bool vy = (yy >= 0 && yy < Hp);
        int yyc = min(max(yy, 0), Hp - 1);
        #pragma unroll
        for (int i = 0; i < 2; i++) {
          int col = c0 + i * 16 + m + dx;
          bool vld = vy && ((unsigned)col < (unsigned)Wp);
          int colc = min(max(col, 0), Wp - 1);
          short8 h = *(const short8*)&in[(ibase + (size_t)yyc * Wp + colc) * 64 + ci0];
          afr[r][i] = vld ? h : zz;
        }
      }
      #pragma unroll
      for (int r = 0; r < 2; r++)
        #pragma unroll
        for (int i = 0; i < 2; i++)
          #pragma unroll
          for (int j = 0; j < 2; j++)
            acc[r][i][j] = __builtin_amdgcn_mfma_f32_16x16x32_bf16(afr[r][i], bfr[j], acc[r][i][j], 0, 0, 0);
    }
  }

  #pragma unroll
  for (int j = 0; j < 2; j++) {
    int co = coW + j * 16 + m;
    float bv = bias[co];
    #pragma unroll
    for (int r = 0; r < 2; r++) {
      #pragma unroll
      for (int i = 0; i < 2; i++) {
        #pragma unroll
        for (int rr = 0; rr < 4; rr++) {
          size_t px = ibase + (size_t)(y0 + r) * Wp + c0 + i * 16 + q * 4 + rr;
          float v = acc[r][i][j][rr] + bv;
          v = v > 0.f ? v : 0.1f * v;
          out[px * 64 + co] = f2b(v);
        }
      }
    }
  }
}

// ---------------- NCHW bf16 -> NHWC bf16 transpose (full batch) ----------------
__global__ __launch_bounds__(256)
void t64b(const ushortt* __restrict__ in, ushortt* __restrict__ out) {
  __shared__ ushortt tl[64 * 65];
  int tid = threadIdx.x;
  int b = blockIdx.y;
  int px0 = blockIdx.x * 64;
  int lpx = tid & 63, c4 = tid >> 6;
  const ushortt* ip = in + (size_t)b * 64 * HWp;
  #pragma unroll
  for (int i = 0; i < 16; i++) {
    int c = c4 + 4 * i;
    tl[lpx * 65 + c] = ip[(size_t)c * HWp + px0 + lpx];
  }
  __syncthreads();
  int ci = tid & 63, pr = tid >> 6;
  #pragma unroll
  for (int i = 0; i < 16; i++) {
    int r = pr + 4 * i;
    out[((size_t)b * HWp + px0 + r) * 64 + ci] = tl[r * 65 + ci];
  }
}

// ---------------- merged weight repack (all segments, 5245 blocks) ----------------
__global__ __launch_bounds__(256)
void repack_all(const float* __restrict__ w1a, const float* __restrict__ w3a,
                const float* __restrict__ w5a, const float* __restrict__ inv2,
                const float* __restrict__ d2, const float* __restrict__ d4,
                const float* __restrict__ d6, const float* __restrict__ ow1,
                const float* __restrict__ ow2, const float* __restrict__ ow3,
                const float* __restrict__ ow4, const float* __restrict__ ow5,
                const float* __restrict__ p1, const float* __restrict__ p2,
                const float* __restrict__ p3, const float* __restrict__ p4,
                ushortt* __restrict__ wb, ushortt* __restrict__ wbi2,
                ushortt* __restrict__ wdwb, ushortt* __restrict__ wc1,
                ushortt* __restrict__ wc2, ushortt* __restrict__ wpw) {
  int b = blockIdx.x;
  int tid = threadIdx.x;
  if (b < 4320) {                       // wie_w1/3/5 -> wb (640-padded, perm)
    int which = b / 1440;
    int idx = (b - which * 1440) * 256 + tid;
    const float* in = which == 0 ? w1a : which == 1 ? w3a : w5a;
    int cop = idx / 576, cip = idx % 576;
    ushortt v = 0;
    if (cop < 576) {
      int co = (cop & 63) * 9 + (cop >> 6);
      int ci = (cip & 63) * 9 + (cip >> 6);
      v = f2b(in[(size_t)co * 576 + ci]);
    }
    wb[(size_t)which * 640 * 576 + idx] = v;
  } else if (b < 4464) {                // inv_w2 -> wbi2
    int idx = (b - 4320) * 256 + tid;
    if (idx < 64 * 576) {
      int co = idx / 576, cip = idx % 576;
      int ci = (cip & 63) * 9 + (cip >> 6);
      wbi2[idx] = f2b(inv2[(size_t)co * 576 + ci]);
    }
  } else if (b < 4525) {                // wie_w2/4/6 dw -> wdwb
    int idx = (b - 4464) * 256 + tid;
    if (idx < 3 * 5184) {
      int which = idx / 5184, r = idx % 5184;
      const float* in = which == 0 ? d2 : which == 1 ? d4 : d6;
      int tap = r / 576, chp = r % 576;
      int ch = (chp & 63) * 9 + (chp >> 6);
      wdwb[idx] = f2b(in[ch * 9 + tap]);
    }
  } else if (b < 4541) {                // off_w1 -> wc1
    int idx = (b - 4525) * 256 + tid;
    if (idx < 4096) wc1[idx] = f2b(ow1[idx]);
  } else if (b < 5117) {                // off_w2..5 -> wc2
    int bb = b - 4541;
    int which = bb / 144;
    int idx = (bb - which * 144) * 256 + tid;
    if (idx < 36864) {
      const float* in = which == 0 ? ow2 : which == 1 ? ow3 : which == 2 ? ow4 : ow5;
      int k = idx >> 12, r = idx & 4095;
      int co = r >> 6, ci = r & 63;
      wc2[which * 36864 + idx] = f2b(in[(size_t)(co * 64 + ci) * 9 + k]);
    }
  } else {                              // enc/dec pw -> wpw
    int bb = b - 5117;
    int which = bb / 32;
    int idx = (bb - which * 32) * 256 + tid;
    if (idx < 8192) {
      const float* in = which == 0 ? p1 : which == 1 ? p2 : which == 2 ? p3 : p4;
      wpw[which * 8192 + idx] = f2b(in[idx]);
    }
  }
}

// ---------------- off_w6 -> NCHW offsets, 8*tanh ----------------
__global__ __launch_bounds__(256)
void off6_nhwc(const ushortt* __restrict__ hi, const float* __restrict__ wgt,
               const float* __restrict__ bias, float* __restrict__ out) {
  __shared__ float Wl[18 * 64];
  for (int i = threadIdx.x; i < 18 * 64; i += 256) Wl[i] = wgt[i];
  __syncthreads();
  int px = blockIdx.x * 256 + threadIdx.x;
  int b = px >> 14, pim = px & 16383;
  float acc[18];
  #pragma unroll
  for (int j = 0; j < 18; j++) acc[j] = 0.f;
  const uint4* ph = (const uint4*)(hi + (size_t)px * 64);
  for (int g = 0; g < 8; g++) {
    uint4 H = ph[g];
    u32 hw[4] = {H.x, H.y, H.z, H.w};
    #pragma unroll
    for (int t = 0; t < 4; t++) {
      float v0 = blo(hw[t]);
      float v1 = bhi(hw[t]);
      int ci = g * 8 + t * 2;
      #pragma unroll
      for (int j = 0; j < 18; j++)
        acc[j] += Wl[j * 64 + ci] * v0 + Wl[j * 64 + ci + 1] * v1;
    }
  }
  #pragma unroll
  for (int j = 0; j < 18; j++)
    out[((size_t)b * 18 + j) * HWp + pim] = 8.f * tanhf(acc[j] + bias[j]);
}

// ---------------- deform v2: 4ch/lane uint2 gathers, 4px/wave, XCD row-aligned ----------------
__global__ __launch_bounds__(256)
void deform_x(const ushortt* __restrict__ xn0, const float* __restrict__ offs0,
              ushortt* __restrict__ xb) {
  int lin = blockIdx.x;
  int xcd = lin & 7, local = lin >> 3;    // [0,256)
  int rowi = local >> 3, bx = local & 7;
  int tid = threadIdx.x;
  int wid = tid >> 6, lane = tid & 63;
  int c4 = lane & 15, ps = lane >> 4;     // 16 lanes/px, 4 ch/lane; 4 px/wave
  int pg = (xcd * 32 + rowi) * 128 + bx * 16 + wid * 4 + ps;
  int bl = pg >> 14, p = pg & 16383;
  const ushortt* xn = xn0 + (size_t)bl * HWp * 64;
  const float* offs = offs0 + (size_t)bl * 18 * HWp;
  int yi = p >> 7, xi = p & 127;
  #pragma unroll
  for (int k = 0; k < 9; k++) {
    float dy = offs[(size_t)(2 * k) * HWp + p];
    float dx = offs[(size_t)(2 * k + 1) * HWp + p];
    float py = (float)yi + (float)(k / 3 - 1) + dy;
    float px = (float)xi + (float)(k % 3 - 1) + dx;
    float y0f = floorf(py), x0f = floorf(px);
    float wy1 = py - y0f, wy0 = 1.f - wy1;
    float wx1 = px - x0f, wx0 = 1.f - wx1;
    int y0 = (int)y0f, x0 = (int)x0f;
    bool vy0 = (y0 >= 0 && y0 < Hp), vy1 = (y0 + 1 >= 0 && y0 + 1 < Hp);
    bool vx0 = (x0 >= 0 && x0 < Wp), vx1 = (x0 + 1 >= 0 && x0 + 1 < Wp);
    int yc0 = min(max(y0, 0), Hp - 1), yc1 = min(max(y0 + 1, 0), Hp - 1);
    int xc0 = min(max(x0, 0), Wp - 1), xc1 = min(max(x0 + 1, 0), Wp - 1);
    float w00 = wy0 * wx0 * ((vy0 && vx0) ? 1.f : 0.f);
    float w01 = wy0 * wx1 * ((vy0 && vx1) ? 1.f : 0.f);
    float w10 = wy1 * wx0 * ((vy1 && vx0) ? 1.f : 0.f);
    float w11 = wy1 * wx1 * ((vy1 && vx1) ? 1.f : 0.f);
    uint2 t00 = *(const uint2*)&xn[(size_t)(yc0 * Wp + xc0) * 64 + c4 * 4];
    uint2 t01 = *(const uint2*)&xn[(size_t)(yc0 * Wp + xc1) * 64 + c4 * 4];
    uint2 t10 = *(const uint2*)&xn[(size_t)(yc1 * Wp + xc0) * 64 + c4 * 4];
    uint2 t11 = *(const uint2*)&xn[(size_t)(yc1 * Wp + xc1) * 64 + c4 * 4];
    float a0 = blo(t00.x) * w00 + blo(t01.x) * w01 + blo(t10.x) * w10 + blo(t11.x) * w11;
    float b0 = bhi(t00.x) * w00 + bhi(t01.x) * w01 + bhi(t10.x) * w10 + bhi(t11.x) * w11;
    float a1 = blo(t00.y) * w00 + blo(t01.y) * w01 + blo(t10.y) * w10 + blo(t11.y) * w11;
    float b1 = bhi(t00.y) * w00 + bhi(t01.y) * w01 + bhi(t10.y) * w10 + bhi(t11.y) * w11;
    uint2 st;
    st.x = (u32)f2b(a0) | (((u32)f2b(b0)) << 16);
    st.y = (u32)f2b(a1) | (((u32)f2b(b1)) << 16);
    *(uint2*)&xb[(size_t)pg * 576 + 64 * k + c4 * 4] = st;
  }
}

// ---------------- MFMA bf16 GEMM, 128x128 tile, XCD-partitioned ----------------
// v2 (measured best): 2-phase double-buffered LDS + swapped-operand coalesced
// epilogue. v3/v4/v5 all regressed -> this is the structure's floor.
__global__ __launch_bounds__(256)
void gemm128(const ushortt* __restrict__ X, const ushortt* __restrict__ Wb,
             ushortt* __restrict__ out) {
  __shared__ ushortt Xs[2][4096];
  __shared__ ushortt Wsh[2][4096];
  int tid = threadIdx.x;
  int lin = blockIdx.x + blockIdx.y * 5;
  int xcd = lin & 7, loc = lin >> 3;
  int co_t = loc % 5;
  int px_t = xcd * 32 + loc / 5;
  int co0 = co_t * 128, px0 = px_t * 128;
  int r0 = tid >> 2;
  int sch = (tid & 3) ^ ((tid >> 3) & 3);
  size_t gx0 = (size_t)(px0 + r0) * 576 + sch * 8;
  size_t gx1 = gx0 + (size_t)64 * 576;
  size_t gw0 = (size_t)(co0 + r0) * 576 + sch * 8;
  size_t gw1 = gw0 + (size_t)64 * 576;
  int wid = tid >> 6, lane = tid & 63;
  int q = lane >> 4, m = lane & 15;
  int qx = (q ^ ((m >> 1) & 3)) * 8;
  int pxh = (wid & 1) * 64, coh = (wid >> 1) * 64;
  float4v acc[4][4];
  #pragma unroll
  for (int i = 0; i < 4; i++)
    #pragma unroll
    for (int j = 0; j < 4; j++) acc[i][j] = (float4v){0.f, 0.f, 0.f, 0.f};

  // prologue: stage K-step 0 into buffer 0
  gll(X + gx0,  &Xs[0][tid * 8]);
  gll(X + gx1,  &Xs[0][2048 + tid * 8]);
  gll(Wb + gw0, &Wsh[0][tid * 8]);
  gll(Wb + gw1, &Wsh[0][2048 + tid * 8]);
  __syncthreads();

  int cur = 0;
  for (int k0 = 0; k0 < 576; k0 += 32) {
    if (k0 + 32 < 576) {               // prefetch next K-step into other buffer
      gll(X + gx0 + k0 + 32,  &Xs[cur ^ 1][tid * 8]);
      gll(X + gx1 + k0 + 32,  &Xs[cur ^ 1][2048 + tid * 8]);
      gll(Wb + gw0 + k0 + 32, &Wsh[cur ^ 1][tid * 8]);
      gll(Wb + gw1 + k0 + 32, &Wsh[cur ^ 1][2048 + tid * 8]);
    }
    short8 a[4], b[4];
    #pragma unroll
    for (int i = 0; i < 4; i++)
      a[i] = *(const short8*)&Xs[cur][(pxh + i * 16 + m) * 32 + qx];
    #pragma unroll
    for (int j = 0; j < 4; j++)
      b[j] = *(const short8*)&Wsh[cur][(coh + j * 16 + m) * 32 + qx];
    #pragma unroll
    for (int i = 0; i < 4; i++)
      #pragma unroll
      for (int j = 0; j < 4; j++)
        acc[i][j] = __builtin_amdgcn_mfma_f32_16x16x32_bf16(b[j], a[i], acc[i][j], 0, 0, 0);
    __syncthreads();                   // drains prefetch (vmcnt0) + LDS reads
    cur ^= 1;
  }

  // epilogue: swapped orientation -> reg index r runs along co (contiguous)
  #pragma unroll
  for (int j = 0; j < 4; j++) {
    int cob = co0 + coh + j * 16 + q * 4;
    if (cob >= 576) continue;
    #pragma unroll
    for (int i = 0; i < 4; i++) {
      size_t px = (size_t)(px0 + pxh + i * 16 + m);
      u32 lo = (u32)f2b(acc[i][j][0]) | (((u32)f2b(acc[i][j][1])) << 16);
      u32 hi = (u32)f2b(acc[i][j][2]) | (((u32)f2b(acc[i][j][3])) << 16);
      uint2 st; st.x = lo; st.y = hi;
      *(uint2*)&out[px * 576 + cob] = st;
    }
  }
}

// ---------------- MFMA bf16 GEMM 576->64 (inv2), out fp32 NCHW, XCD row-aligned ----------------
// v2: 2-phase double-buffered K-loop (verified transformation).
__global__ __launch_bounds__(256)
void gemm64o2(const ushortt* __restrict__ X, const ushortt* __restrict__ Wb,
              float* __restrict__ outv) {
  __shared__ ushortt Xs[2][4096];
  __shared__ ushortt Wsh[2][2048];
  int tid = threadIdx.x;
  int lin = blockIdx.x;
  int xcd = lin & 7, local = lin >> 3;      // [0,32)
  int px0 = (xcd * 32 + local) * 128;
  int srow = tid >> 2;
  int sch = (tid & 3) ^ ((tid >> 3) & 3);
  size_t gxo0 = (size_t)(px0 + srow) * 576 + sch * 8;
  size_t gxo1 = gxo0 + (size_t)64 * 576;
  size_t gwo  = (size_t)srow * 576 + sch * 8;
  int wid = tid >> 6, lane = tid & 63;
  int q = lane >> 4, m = lane & 15;
  int qx = (q ^ ((m >> 1) & 3)) * 8;
  int pxh = (wid & 1) * 64, coh = (wid >> 1) * 32;
  float4v acc[4][2];
  #pragma unroll
  for (int i = 0; i < 4; i++)
    #pragma unroll
    for (int j = 0; j < 2; j++) acc[i][j] = (float4v){0.f, 0.f, 0.f, 0.f};

  // prologue: stage K-step 0 into buffer 0
  gll(X + gxo0,  &Xs[0][tid * 8]);
  gll(X + gxo1,  &Xs[0][2048 + tid * 8]);
  gll(Wb + gwo,  &Wsh[0][tid * 8]);
  __syncthreads();

  int cur = 0;
  for (int k0 = 0; k0 < 576; k0 += 32) {
    if (k0 + 32 < 576) {               // prefetch next K-step into other buffer
      gll(X + gxo0 + k0 + 32,  &Xs[cur ^ 1][tid * 8]);
      gll(X + gxo1 + k0 + 32,  &Xs[cur ^ 1][2048 + tid * 8]);
      gll(Wb + gwo + k0 + 32,  &Wsh[cur ^ 1][tid * 8]);
    }
    short8 a[4], b[2];
    #pragma unroll
    for (int i = 0; i < 4; i++)
      a[i] = *(const short8*)&Xs[cur][(pxh + i * 16 + m) * 32 + qx];
    #pragma unroll
    for (int j = 0; j < 2; j++)
      b[j] = *(const short8*)&Wsh[cur][(coh + j * 16 + m) * 32 + qx];
    #pragma unroll
    for (int i = 0; i < 4; i++)
      #pragma unroll
      for (int j = 0; j < 2; j++)
        acc[i][j] = __builtin_amdgcn_mfma_f32_16x16x32_bf16(a[i], b[j], acc[i][j], 0, 0, 0);
    __syncthreads();                   // drains prefetch + LDS reads
    cur ^= 1;
  }

  #pragma unroll
  for (int j = 0; j < 2; j++) {
    int co = coh + j * 16 + m;
    #pragma unroll
    for (int i = 0; i < 4; i++) {
      int pxb = px0 + pxh + i * 16 + q * 4;
      int bl = pxb >> 14, pim = pxb & 16383;
      float4 r;
      r.x = acc[i][j][0]; r.y = acc[i][j][1];
      r.z = acc[i][j][2]; r.w = acc[i][j][3];
      *(float4*)&outv[(size_t)(bl * 64 + co) * HWp + pim] = r;
    }
  }
}

// ---------------- depthwise 3x3 NHWC bf16 v3: XCD row-aligned, 8ch x 4 rows ----------------
template<int ACT>
__global__ __launch_bounds__(256)
void dw3x3_v3(const ushortt* __restrict__ in, const ushortt* __restrict__ wt,
              ushortt* __restrict__ out) {
  int lin = blockIdx.x;
  int xcd = lin & 7, local = lin >> 3;     // [0,344)
  int g = local / 43, bxq = local - g * 43;
  int rg = xcd * 8 + g;                    // combined row-group [0,64)
  int bz = rg >> 5, by = rg & 31;
  int tid = threadIdx.x;
  int pxl = tid / 72;
  int gg = tid - pxl * 72;
  if (pxl >= 3) return;
  int x = bxq * 3 + pxl;
  if (x >= Wp) return;
  int y0 = by * 4;
  size_t bbase = (size_t)bz * HWp;

  float w[9][8];
  #pragma unroll
  for (int t = 0; t < 9; t++) {
    uint4 wv = *(const uint4*)&wt[t * 576 + gg * 8];
    u32 wsw[4] = {wv.x, wv.y, wv.z, wv.w};
    #pragma unroll
    for (int p = 0; p < 4; p++) {
      w[t][2 * p]     = blo(wsw[p]);
      w[t][2 * p + 1] = bhi(wsw[p]);
    }
  }
  float acc[4][8];
  #pragma unroll
  for (int o = 0; o < 4; o++)
    #pragma unroll
    for (int c = 0; c < 8; c++) acc[o][c] = 0.f;

  #pragma unroll
  for (int ri = 0; ri < 6; ri++) {
    int yy = y0 - 1 + ri;
    bool vr = (yy >= 0 && yy < Hp);
    float v[3][8];
    #pragma unroll
    for (int dx = 0; dx < 3; dx++) {
      int xx = x + dx - 1;
      uint4 t4 = {0, 0, 0, 0};
      if (vr && xx >= 0 && xx < Wp)
        t4 = *(const uint4*)&in[(bbase + (size_t)yy * Wp + xx) * 576 + gg * 8];
      u32 tw[4] = {t4.x, t4.y, t4.z, t4.w};
      #pragma unroll
      for (int p = 0; p < 4; p++) {
        v[dx][2 * p]     = blo(tw[p]);
        v[dx][2 * p + 1] = bhi(tw[p]);
      }
    }
    #pragma unroll
    for (int o = 0; o < 4; o++) {
      int dy = ri - o;
      if (dy < 0 || dy > 2) continue;
      #pragma unroll
      for (int dx = 0; dx < 3; dx++)
        #pragma unroll
        for (int c = 0; c < 8; c++)
          acc[o][c] += w[dy * 3 + dx][c] * v[dx][c];
    }
  }

  #pragma unroll
  for (int o = 0; o < 4; o++) {
    int yy = y0 + o;
    u32 pk[4];
    #pragma unroll
    for (int p = 0; p < 4; p++) {
      float r0 = acc[o][2 * p], r1 = acc[o][2 * p + 1];
      if (ACT == 1) { r0 = fmaxf(r0, 0.f); r1 = fmaxf(r1, 0.f); }
      else { r0 = 1.f / (1.f + __expf(-r0)); r1 = 1.f / (1.f + __expf(-r1)); }
      pk[p] = (u32)f2b(r0) | (((u32)f2b(r1)) << 16);
    }
    uint4 o4; o4.x = pk[0]; o4.y = pk[1]; o4.z = pk[2]; o4.w = pk[3];
    *(uint4*)&out[(bbase + (size_t)yy * Wp + x) * 576 + gg * 8] = o4;
  }
}

// ---------------- g9inv2 v2 (best measured): 4 px/thread, 16 px/block, grid 2048 ----------------
__global__ __launch_bounds__(256)
void g9inv2(const ushortt* __restrict__ wien, const ushortt* __restrict__ xb,
            const float* __restrict__ wdct, const float* __restrict__ winv,
            ushortt* __restrict__ outb) {
  __shared__ float Wd[5184];
  __shared__ float Wi[5184];
  for (int i = threadIdx.x; i < 5184; i += 256) {
    Wd[i] = wdct[i];
    Wi[i] = winv[i];
  }
  __syncthreads();
  int lin = blockIdx.x;
  int xcd = lin & 7, local = lin >> 3;     // [0,256)
  int rowi = local >> 3, bx = local & 7;
  int pslot = threadIdx.x >> 6;
  int c = threadIdx.x & 63;
  size_t px0 = (size_t)((xcd * 32 + rowi) * 128 + bx * 16 + pslot * 4);
  const float* wd = &Wd[c * 81];
  const float* wi = &Wi[c * 81];

  float xr[4][9];
  #pragma unroll
  for (int u = 0; u < 4; u++)
    #pragma unroll
    for (int t = 0; t < 9; t++)
      xr[u][t] = b2f(xb[(px0 + u) * 576 + 64 * t + c]);

  float wv[4][9];
  #pragma unroll
  for (int u = 0; u < 4; u++)
    #pragma unroll
    for (int o = 0; o < 9; o++)
      wv[u][o] = b2f(wien[(px0 + u) * 576 + 64 * o + c]);

  float v[4][9];
  #pragma unroll
  for (int o = 0; o < 9; o++) {
    #pragma unroll
    for (int u = 0; u < 4; u++) {
      float d = 0.f;
      #pragma unroll
      for (int t = 0; t < 9; t++) d += wd[o * 9 + t] * xr[u][t];
      v[u][o] = wv[u][o] * d;
    }
  }
  #pragma unroll
  for (int j = 0; j < 9; j++) {
    #pragma unroll
    for (int u = 0; u < 4; u++) {
      float a = 0.f;
      #pragma unroll
      for (int o = 0; o < 9; o++) a += wi[j * 9 + o] * v[u][o];
      outb[(px0 + u) * 576 + 64 * j + c] = f2b(a);
    }
  }
}

// ---------------- launch ----------------
extern "C" void kernel_launch(void* const* d_in, const int* in_sizes, int n_in,
                              void* d_out, int out_size, void* d_ws, size_t ws_size,
                              hipStream_t stream) {
  const float* x       = (const float*)d_in[0];
  const float* enc_dw  = (const float*)d_in[1];
  const float* enc_pw1 = (const float*)d_in[2];
  const float* enc_pw2 = (const float*)d_in[3];
  const float* dec_dw  = (const float*)d_in[4];
  const float* dec_pw1 = (const float*)d_in[5];
  const float* dec_pw2 = (const float*)d_in[6];
  const float* off_w1  = (const float*)d_in[7];
  const float* off_b1  = (const float*)d_in[8];
  const float* off_w2  = (const float*)d_in[9];
  const float* off_b2  = (const float*)d_in[10];
  const float* off_w3  = (const float*)d_in[11];
  const float* off_b3  = (const float*)d_in[12];
  const float* off_w4  = (const float*)d_in[13];
  const float* off_b4  = (const float*)d_in[14];
  const float* off_w5  = (const float*)d_in[15];
  const float* off_b5  = (const float*)d_in[16];
  const float* off_w6  = (const float*)d_in[17];
  const float* off_b6  = (const float*)d_in[18];
  const float* dct_w   = (const float*)d_in[19];
  const float* wie_w1  = (const float*)d_in[20];
  const float* wie_w2  = (const float*)d_in[21];
  const float* wie_w3  = (const float*)d_in[22];
  const float* wie_w4  = (const float*)d_in[23];
  const float* wie_w5  = (const float*)d_in[24];
  const float* wie_w6  = (const float*)d_in[25];
  const float* inv_w1  = (const float*)d_in[26];
  const float* inv_w2  = (const float*)d_in[27];
  float* outp = (float*)d_out;

  const size_t NP = (size_t)Bp * HWp;
  const size_t REQ_FLOATS = NP * 64 + NP * 64 + NP * 128 +
                            2 * (size_t)HWp * CKp + (size_t)HWp * CKp;
  if (ws_size < REQ_FLOATS * sizeof(float)) return;

  float* ws  = (float*)d_ws;
  float* x1  = ws;
  float* t0  = x1 + NP * 64;
  float* t1  = t0 + NP * 64;
  float* bigA = t1 + NP * 128;
  float* bigB = bigA + (size_t)HWp * CKp;
  float* bigC = bigB + (size_t)HWp * CKp;
  ushortt* R1 = (ushortt*)bigA;
  ushortt* R2 = (ushortt*)bigB;
  ushortt* R3 = (ushortt*)bigC;
  ushortt* e1 = (ushortt*)bigA;

  float* wreg = t0 + NP * 18;
  ushortt* wb  = (ushortt*)wreg;
  ushortt* wbi2 = wb + 3 * 640 * 576;
  ushortt* wdwb = wbi2 + 64 * 576;
  ushortt* wc1  = wdwb + 3 * 5184;
  ushortt* wc2  = wc1 + 4096;
  ushortt* wpw  = wc2 + 4 * 36864;

  ushortt* xnAll = (ushortt*)t1;
  ushortt* oA = xnAll + NP * 64;
  ushortt* oB = oA + NP * 64;

  float* offs = t0;
  float* mid  = x1;

  dim3 blk(256);

  // ---- enc ConvNeXt: dw7 fp32->bf16, pw via bf16 MFMA ----
  dwconv7_lds<<<dim3(Hp / 2, Bp * Cp), blk, 0, stream>>>(x, enc_dw, (ushortt*)t0);
  t64b<<<dim3(HWp / 64, Bp), blk, 0, stream>>>((const ushortt*)t0, oA);

  // ---- merged weight repack ----
  repack_all<<<dim3(5245), blk, 0, stream>>>(
      wie_w1, wie_w3, wie_w5, inv_w2, wie_w2, wie_w4, wie_w6, off_w1,
      off_w2, off_w3, off_w4, off_w5, enc_pw1, enc_pw2, dec_pw1, dec_pw2,
      wb, wbi2, wdwb, wc1, wc2, wpw);

  pw_bf<64, 1, 0><<<dim3(NP / 128, 2), blk, 0, stream>>>(oA, wpw, nullptr, e1, 128);
  pw_bf<128, 0, 1><<<dim3(NP / 128, 1), blk, 0, stream>>>(e1, wpw + 8192, x, xnAll, 64);

  // ---- offset CNN (full batch, bf16 MFMA, NHWC; 3x3 layers 2-row) ----
  conv_bf<1><<<dim3(HWp / 64, Bp), blk, 0, stream>>>(xnAll, wc1, off_b1, oA);
  conv_bf9r2<<<dim3(128, Bp), blk, 0, stream>>>(oA, wc2,             off_b2, oB);
  conv_bf9r2<<<dim3(128, Bp), blk, 0, stream>>>(oB, wc2 + 36864,     off_b3, oA);
  conv_bf9r2<<<dim3(128, Bp), blk, 0, stream>>>(oA, wc2 + 2 * 36864, off_b4, oB);
  conv_bf9r2<<<dim3(128, Bp), blk, 0, stream>>>(oB, wc2 + 3 * 36864, off_b5, oA);
  off6_nhwc<<<dim3(NP / 256), blk, 0, stream>>>(oA, off_w6, off_b6, offs);

  // ---- 576-channel middle: 2 batches per pass; xb persists in R2 ----
  for (int bp = 0; bp < 2; bp++) {
    const ushortt* xn0 = xnAll + (size_t)(2 * bp) * HWp * 64;
    const float* off0 = offs + (size_t)(2 * bp) * 18 * HWp;
    float* mid0 = mid + (size_t)(2 * bp) * 64 * HWp;

    deform_x<<<dim3(2048), blk, 0, stream>>>(xn0, off0, R2);
    gemm128<<<dim3(5, 256), blk, 0, stream>>>(R2, wb, R3);
    dw3x3_v3<1><<<dim3(2752), blk, 0, stream>>>(R3, wdwb, R1);
    gemm128<<<dim3(5, 256), blk, 0, stream>>>(R1, wb + 640 * 576, R3);
    dw3x3_v3<1><<<dim3(2752), blk, 0, stream>>>(R3, wdwb + 5184, R1);
    gemm128<<<dim3(5, 256), blk, 0, stream>>>(R1, wb + 2 * 640 * 576, R3);
    dw3x3_v3<2><<<dim3(2752), blk, 0, stream>>>(R3, wdwb + 2 * 5184, R1);  // wiener
    g9inv2<<<dim3(2048), blk, 0, stream>>>(R1, R2, dct_w, inv_w1, R3);
    gemm64o2<<<dim3(256), blk, 0, stream>>>(R3, wbi2, mid0);
  }

  // ---- dec ConvNeXt: dw7 fp32->bf16 (tmp in bigB), pw via bf16 MFMA ----
  dwconv7_lds<<<dim3(Hp / 2, Bp * Cp), blk, 0, stream>>>(mid, dec_dw, (ushortt*)bigB);
  t64b<<<dim3(HWp / 64, Bp), blk, 0, stream>>>((const ushortt*)bigB, oA);
  pw_bf<64, 1, 0><<<dim3(NP / 128, 2), blk, 0, stream>>>(oA, wpw + 2 * 8192, nullptr, e1, 128);
  pw_bf<128, 0, 2><<<dim3(NP / 128, 1), blk, 0, stream>>>(e1, wpw + 3 * 8192, mid, outp, 64);
}